// Round 5
// baseline (14799.333 us; speedup 1.0000x reference)
//
#include <hip/hip_runtime.h>
#include <hip/hip_bf16.h>

#define B_ 64
#define N_ 1024
#define E_ 512
#define D_ 1024
#define M_ 16
#define T_ 12
#define P_ 2048
#define HS_ 2048
#define HN_ 64
#define C_ 4
#define NH_ 8
#define DH_ 64
#define NBLK_ 512

typedef __attribute__((ext_vector_type(8))) short bf16x8;
typedef __attribute__((ext_vector_type(4))) float f32x4;

__device__ __forceinline__ float bf2f(unsigned int u) {
    union { unsigned int i; float f; } c; c.i = (u & 0xffffu) << 16; return c.f;
}
__device__ __forceinline__ unsigned short f2bf(float f) {
    union { float f; unsigned int i; } c; c.f = f;
    unsigned int x = c.i;
    unsigned int r = x + 0x7fffu + ((x >> 16) & 1u);
    return (unsigned short)(r >> 16);
}
__device__ __forceinline__ float dot2bf(unsigned int a, unsigned int b) {
    union { unsigned int i; float f; } al, ah, bl, bh;
    al.i = a << 16; ah.i = a & 0xffff0000u;
    bl.i = b << 16; bh.i = b & 0xffff0000u;
    return al.f * bl.f + ah.f * bh.f;
}

// ---------------- init state (+ grid-barrier vars) ----------------
__global__ void init_kernel(unsigned short* s_a_bf, float* a_a, float* b_a, float* a_o, float* b_o,
                            float* z, unsigned int* bar) {
    int i = blockIdx.x * 256 + threadIdx.x;
    if (i < B_ * P_) { a_a[i] = 0.f; b_a[i] = 1.f; a_o[i] = 0.f; b_o[i] = 1.f; s_a_bf[i] = 0; }
    if (i < B_ * D_) z[i] = 0.f;
    if (i < 2) bar[i] = 0u;
}

// ---------------- f32 -> bf16 conversion ----------------
__global__ __launch_bounds__(256) void cvt_bf16_kernel(const float* __restrict__ in,
                                                       unsigned short* __restrict__ out, int n4) {
    int i = blockIdx.x * 256 + threadIdx.x;
    if (i < n4) {
        float4 v = ((const float4*)in)[i];
        ushort4 o;
        o.x = f2bf(v.x); o.y = f2bf(v.y); o.z = f2bf(v.z); o.w = f2bf(v.w);
        ((ushort4*)out)[i] = o;
    }
}

// ---------------- interleave gate/cand rows ----------------
__global__ __launch_bounds__(256) void cvt_ilv_kernel(const float* __restrict__ g,
                                                      const float* __restrict__ c,
                                                      unsigned short* __restrict__ out) {
    int r = blockIdx.x;  // 0..2047
    const float* src = (r & 1) ? (c + (size_t)(r >> 1) * 1536) : (g + (size_t)(r >> 1) * 1536);
    for (int k = threadIdx.x * 4; k < 1536; k += 1024) {
        float4 v = *(const float4*)(src + k);
        ushort4 o;
        o.x = f2bf(v.x); o.y = f2bf(v.y); o.z = f2bf(v.z); o.w = f2bf(v.w);
        *(ushort4*)(out + (size_t)r * 1536 + k) = o;
    }
}

// ---------------- transpose + cvt ----------------
__global__ __launch_bounds__(256) void transpose_cvt_kernel(const float* __restrict__ in,
                                                            unsigned short* __restrict__ out,
                                                            int R, int Ccols) {
    __shared__ float tb[32][33];
    int c0 = blockIdx.x * 32, r0 = blockIdx.y * 32;
    int tx = threadIdx.x & 31, ty = threadIdx.x >> 5;
#pragma unroll
    for (int i = 0; i < 32; i += 8) tb[ty + i][tx] = in[(size_t)(r0 + ty + i) * Ccols + c0 + tx];
    __syncthreads();
#pragma unroll
    for (int i = 0; i < 32; i += 8) out[(size_t)(c0 + ty + i) * R + r0 + tx] = f2bf(tb[tx][ty + i]);
}

// ---------------- combined query bias ----------------
__global__ __launch_bounds__(256) void bcomb_kernel(const float* __restrict__ in_proj_w,
                                                    const float* __restrict__ in_proj_b,
                                                    const float* __restrict__ q_b,
                                                    float* __restrict__ bc) {
    int e = blockIdx.x * 256 + threadIdx.x;
    if (e < E_) {
        const float* wr = in_proj_w + (size_t)e * E_;
        float s = in_proj_b[e];
        for (int k = 0; k < E_; k += 4) {
            float4 w4 = *(const float4*)(wr + k);
            float4 q4 = *(const float4*)(q_b + k);
            s += w4.x * q4.x + w4.y * q4.y + w4.z * q4.z + w4.w * q4.w;
        }
        bc[e] = s;
    }
}

// ---------------- big bf16 MFMA GEMM (128x128 tile), improved 2-way swizzle + XCD swizzle ----------------
template <bool HAS_BIAS>
__global__ __launch_bounds__(256) void gemm_bt_kernel(const unsigned short* __restrict__ A,
                                                      const unsigned short* __restrict__ Bt,
                                                      const float* __restrict__ bias,
                                                      unsigned short* __restrict__ C,
                                                      int M, int N, int K) {
    __shared__ __align__(16) unsigned short ldsA[2][4096];
    __shared__ __align__(16) unsigned short ldsB[2][4096];
    int id = blockIdx.y * gridDim.x + blockIdx.x;
    int nwg = gridDim.x * gridDim.y;
    int swz = (id & 7) * (nwg >> 3) + (id >> 3);
    int bx = swz % gridDim.x, by = swz / gridDim.x;
    int m0 = by * 128;
    int n0 = bx * 128;
    int tid = threadIdx.x;
    int wv = tid >> 6, l = tid & 63;
    int wr = wv >> 1, wc = wv & 1;
    int lr = l & 15, lg = l >> 4;
    f32x4 acc[4][4] = {};

    auto stage = [&](int buf, int kt) {
        int k0 = kt * 32;
#pragma unroll
        for (int i = 0; i < 2; i++) {
            int tsk = tid + 256 * i;
            int r = tsk >> 2, g = tsk & 3;
            int gs = (g ^ (r & 3) ^ ((r >> 2) & 3)) * 8;
            __builtin_amdgcn_global_load_lds(
                (const __attribute__((address_space(1))) void*)(A + (size_t)(m0 + r) * K + k0 + gs),
                (__attribute__((address_space(3))) void*)&ldsA[buf][tsk * 8], 16, 0, 0);
        }
#pragma unroll
        for (int i = 0; i < 2; i++) {
            int tsk = tid + 256 * i;
            int r = tsk >> 2, g = tsk & 3;
            int gs = (g ^ (r & 3) ^ ((r >> 2) & 3)) * 8;
            __builtin_amdgcn_global_load_lds(
                (const __attribute__((address_space(1))) void*)(Bt + (size_t)(n0 + r) * K + k0 + gs),
                (__attribute__((address_space(3))) void*)&ldsB[buf][tsk * 8], 16, 0, 0);
        }
    };

    int nt = K >> 5;
    stage(0, 0);
    for (int t = 0; t < nt; t++) {
        int cur = t & 1;
        if (t + 1 < nt) {
            stage(cur ^ 1, t + 1);
            asm volatile("s_waitcnt vmcnt(4)" ::: "memory");
        } else {
            asm volatile("s_waitcnt vmcnt(0)" ::: "memory");
        }
        __builtin_amdgcn_s_barrier();
        bf16x8 af[4], bfr[4];
#pragma unroll
        for (int mi = 0; mi < 4; mi++) {
            int r = wr * 64 + mi * 16 + lr;
            int slot = lg ^ (r & 3) ^ ((r >> 2) & 3);
            af[mi] = *(const bf16x8*)&ldsA[cur][r * 32 + (slot << 3)];
        }
#pragma unroll
        for (int ni = 0; ni < 4; ni++) {
            int c = wc * 64 + ni * 16 + lr;
            int slot = lg ^ (c & 3) ^ ((c >> 2) & 3);
            bfr[ni] = *(const bf16x8*)&ldsB[cur][c * 32 + (slot << 3)];
        }
#pragma unroll
        for (int mi = 0; mi < 4; mi++)
#pragma unroll
            for (int ni = 0; ni < 4; ni++)
                acc[mi][ni] = __builtin_amdgcn_mfma_f32_16x16x32_bf16(af[mi], bfr[ni], acc[mi][ni], 0, 0, 0);
        __builtin_amdgcn_s_barrier();
    }
#pragma unroll
    for (int ni = 0; ni < 4; ni++) {
        int col = n0 + wc * 64 + ni * 16 + lr;
        float bv = HAS_BIAS ? bias[col] : 0.0f;
#pragma unroll
        for (int mi = 0; mi < 4; mi++) {
            int row = m0 + wr * 64 + mi * 16 + lg * 4;
#pragma unroll
            for (int r = 0; r < 4; r++) {
                C[(size_t)(row + r) * N + col] = f2bf(acc[mi][ni][r] + bv);
            }
        }
    }
}

// ================= persistent tick kernel =================
struct TickArgs {
    const unsigned short* kvbuf;
    const unsigned short* Wc_bf;
    const float* b_comb;
    const unsigned short* Wout_bf;
    const float* out_proj_b;
    const float* o_ln_g; const float* o_ln_b;
    const float* z_ln_g; const float* z_ln_b;
    const unsigned short* Wgc_bf; const float* gate_b; const float* cand_b;
    const unsigned short* Ws1_bf; const float* syn1_b;
    const unsigned short* Ws2_bf; const float* syn2_b;
    const unsigned short* nlm1w_bf; const float* nlm1_b;
    const float* nlm2_w; const float* nlm2_b;
    const float* head_w; const float* head_b;
    const int* act_l; const int* act_r; const int* out_l; const int* out_r;
    const float* raw_a; const float* raw_o;
    unsigned short* s_a_bf;
    unsigned short* o_bf;
    float* opre;
    unsigned short* u_bf;
    unsigned short* fused_bf;
    float* zn32;
    unsigned short* tbuf_bf;
    float* AbufT;
    float* zbuf;
    float* a_a; float* b_a; float* a_o; float* b_o;
    float* out_logits; float* out_cert; float* out_zt;
    unsigned int* bar;
};

__device__ __forceinline__ void grid_barrier(unsigned int* bar) {
    __syncthreads();
    if (threadIdx.x == 0) {
        unsigned int* cnt = bar;
        unsigned int* gen = bar + 1;
        unsigned int g = __hip_atomic_load(gen, __ATOMIC_RELAXED, __HIP_MEMORY_SCOPE_AGENT);
        unsigned int arrived = __hip_atomic_fetch_add(cnt, 1u, __ATOMIC_ACQ_REL, __HIP_MEMORY_SCOPE_AGENT) + 1;
        if (arrived == NBLK_) {
            __hip_atomic_store(cnt, 0u, __ATOMIC_RELAXED, __HIP_MEMORY_SCOPE_AGENT);
            __hip_atomic_fetch_add(gen, 1u, __ATOMIC_ACQ_REL, __HIP_MEMORY_SCOPE_AGENT);
        } else {
            while (__hip_atomic_load(gen, __ATOMIC_ACQUIRE, __HIP_MEMORY_SCOPE_AGENT) == g)
                __builtin_amdgcn_s_sleep(8);
        }
    }
    __syncthreads();
}

// ---- phase: qh (fused) + attention; one block per (b,h) ----
__device__ __forceinline__ void phase_qh_attn(const TickArgs& ta, unsigned char* smem) {
    int vb = blockIdx.x;
    int b = vb >> 3, h = vb & 7;
    float* sc = (float*)smem;          // 1024
    float* qv = sc + 1024;             // 64
    float* red = qv + 64;              // 8
    float* opart = red + 8;            // 4*64
    int tid = threadIdx.x;
    int w = tid >> 6, lane = tid & 63;
    // ---- qh: q = s_a @ Wc^T + b_comb (per-head 64 cols) ----
    uint4 sa[4];
#pragma unroll
    for (int i = 0; i < 4; i++)
        sa[i] = *(const uint4*)(ta.s_a_bf + (size_t)b * P_ + i * 512 + lane * 8);
    for (int cg = 0; cg < 16; cg++) {
        int col = cg * 4 + w;
        const unsigned short* wr = ta.Wc_bf + (size_t)(h * 64 + col) * P_;
        float acc = 0.f;
#pragma unroll
        for (int i = 0; i < 4; i++) {
            uint4 wv = *(const uint4*)(wr + i * 512 + lane * 8);
            acc += dot2bf(wv.x, sa[i].x) + dot2bf(wv.y, sa[i].y)
                 + dot2bf(wv.z, sa[i].z) + dot2bf(wv.w, sa[i].w);
        }
#pragma unroll
        for (int off = 32; off >= 1; off >>= 1) acc += __shfl_xor(acc, off, 64);
        if (lane == 0) qv[col] = acc + ta.b_comb[h * 64 + col];
    }
    __syncthreads();
    // ---- scores ----
    const unsigned short* kb = ta.kvbuf + (size_t)b * N_ * 1024 + h * DH_;
    float myv[4];
#pragma unroll
    for (int i = 0; i < 4; i++) {
        int n = tid + i * 256;
        const unsigned short* kr = kb + (size_t)n * 1024;
        float s = 0.f;
#pragma unroll
        for (int d = 0; d < DH_; d += 8) {
            uint4 pk = *(const uint4*)(kr + d);
            s += bf2f(pk.x) * qv[d + 0] + bf2f(pk.x >> 16) * qv[d + 1]
               + bf2f(pk.y) * qv[d + 2] + bf2f(pk.y >> 16) * qv[d + 3]
               + bf2f(pk.z) * qv[d + 4] + bf2f(pk.z >> 16) * qv[d + 5]
               + bf2f(pk.w) * qv[d + 6] + bf2f(pk.w >> 16) * qv[d + 7];
        }
        myv[i] = s * 0.125f;
    }
    float m = fmaxf(fmaxf(myv[0], myv[1]), fmaxf(myv[2], myv[3]));
#pragma unroll
    for (int off = 32; off >= 1; off >>= 1) m = fmaxf(m, __shfl_xor(m, off, 64));
    if (lane == 0) red[w] = m;
    __syncthreads();
    m = fmaxf(fmaxf(red[0], red[1]), fmaxf(red[2], red[3]));
    float s = 0.f;
#pragma unroll
    for (int i = 0; i < 4; i++) {
        float e = expf(myv[i] - m);
        sc[tid + i * 256] = e;
        s += e;
    }
#pragma unroll
    for (int off = 32; off >= 1; off >>= 1) s += __shfl_xor(s, off, 64);
    if (lane == 0) red[4 + w] = s;
    __syncthreads();
    float inv = 1.0f / (red[4] + red[5] + red[6] + red[7]);
    // ---- V pass ----
    const unsigned short* vbp = ta.kvbuf + (size_t)b * N_ * 1024 + E_ + h * DH_;
    int ng = lane >> 4, d4 = (lane & 15) << 2;
    float a0 = 0.f, a1 = 0.f, a2 = 0.f, a3 = 0.f;
    int n0 = w * 256;
    for (int i = 0; i < 64; i++) {
        int n = n0 + i * 4 + ng;
        uint2 pv = *(const uint2*)(vbp + (size_t)n * 1024 + d4);
        float sv = sc[n];
        a0 += sv * bf2f(pv.x);
        a1 += sv * bf2f(pv.x >> 16);
        a2 += sv * bf2f(pv.y);
        a3 += sv * bf2f(pv.y >> 16);
    }
    a0 += __shfl_xor(a0, 16, 64); a0 += __shfl_xor(a0, 32, 64);
    a1 += __shfl_xor(a1, 16, 64); a1 += __shfl_xor(a1, 32, 64);
    a2 += __shfl_xor(a2, 16, 64); a2 += __shfl_xor(a2, 32, 64);
    a3 += __shfl_xor(a3, 16, 64); a3 += __shfl_xor(a3, 32, 64);
    if (lane < 16) {
        opart[w * 64 + d4 + 0] = a0;
        opart[w * 64 + d4 + 1] = a1;
        opart[w * 64 + d4 + 2] = a2;
        opart[w * 64 + d4 + 3] = a3;
    }
    __syncthreads();
    if (tid < DH_) {
        float r = (opart[tid] + opart[64 + tid] + opart[128 + tid] + opart[192 + tid]) * inv;
        ta.o_bf[(size_t)b * E_ + h * DH_ + tid] = f2bf(r);
    }
}

// ---- phase: batch-64 GEMM 64x16 tile, 4-wave K-split, fused epilogue ----
template <int EPI>
__device__ __forceinline__ void phase_gemmNK(const unsigned short* A, const unsigned short* W,
                                             const float* bias0, const float* bias1,
                                             const float* zn32p, void* outp,
                                             int N, int K, unsigned char* smem, int nvb) {
    int vb = blockIdx.x;
    if (vb >= nvb) return;
    unsigned short (*ldsA)[2][2048] = (unsigned short(*)[2][2048])smem;
    unsigned short (*ldsB)[2][512] = (unsigned short(*)[2][512])(smem + 32768);
    int n0 = vb * 16;
    int tid = threadIdx.x;
    int w = tid >> 6, l = tid & 63;
    int Kw = K >> 2;
    int kb = w * Kw;
    int lr = l & 15, lg = l >> 4;
    int ar = l >> 2, ag = l & 3;
    f32x4 acc[4] = {};

    auto stage = [&](int buf, int kt) {
        int k0 = kb + (kt << 5);
#pragma unroll
        for (int i = 0; i < 4; i++) {
            int row = i * 16 + ar;
            int gs = (ag ^ (row & 3) ^ ((row >> 2) & 3)) << 3;
            __builtin_amdgcn_global_load_lds(
                (const __attribute__((address_space(1))) void*)(A + (size_t)row * K + k0 + gs),
                (__attribute__((address_space(3))) void*)&ldsA[w][buf][i * 512 + l * 8], 16, 0, 0);
        }
        {
            int col = ar;
            int gs = (ag ^ (col & 3) ^ ((col >> 2) & 3)) << 3;
            __builtin_amdgcn_global_load_lds(
                (const __attribute__((address_space(1))) void*)(W + (size_t)(n0 + col) * K + k0 + gs),
                (__attribute__((address_space(3))) void*)&ldsB[w][buf][l * 8], 16, 0, 0);
        }
    };

    int nt = Kw >> 5;
    stage(0, 0);
    for (int t = 0; t < nt; t++) {
        int cur = t & 1;
        if (t + 1 < nt) {
            stage(cur ^ 1, t + 1);
            asm volatile("s_waitcnt vmcnt(5)" ::: "memory");
        } else {
            asm volatile("s_waitcnt vmcnt(0)" ::: "memory");
        }
        int bslot = lg ^ (lr & 3) ^ ((lr >> 2) & 3);
        bf16x8 bf = *(const bf16x8*)&ldsB[w][cur][lr * 32 + (bslot << 3)];
#pragma unroll
        for (int mi = 0; mi < 4; mi++) {
            int rr = mi * 16 + lr;
            int slot = lg ^ (rr & 3) ^ ((rr >> 2) & 3);
            bf16x8 af = *(const bf16x8*)&ldsA[w][cur][rr * 32 + (slot << 3)];
            acc[mi] = __builtin_amdgcn_mfma_f32_16x16x32_bf16(af, bf, acc[mi], 0, 0, 0);
        }
    }
    __syncthreads();
    float* red = (float*)smem;  // [4][64][16]
#pragma unroll
    for (int mi = 0; mi < 4; mi++) {
        int row = mi * 16 + lg * 4;
#pragma unroll
        for (int q = 0; q < 4; q++) red[w * 1024 + (row + q) * 16 + lr] = acc[mi][q];
    }
    __syncthreads();
    int b = tid >> 2, c4 = (tid & 3) << 2;
    f32x4 s = *(f32x4*)&red[b * 16 + c4];
#pragma unroll
    for (int ww = 1; ww < 4; ww++) {
        f32x4 v = *(f32x4*)&red[ww * 1024 + b * 16 + c4];
        s[0] += v[0]; s[1] += v[1]; s[2] += v[2]; s[3] += v[3];
    }
    int col = n0 + c4;
    if (EPI == 1) {
        float* out = (float*)outp;
        *(f32x4*)(out + (size_t)b * N + col) = s;
    } else if (EPI == 2) {
        unsigned short* out = (unsigned short*)outp;
        int j0 = col >> 1;
#pragma unroll
        for (int pp = 0; pp < 2; pp++) {
            int j = j0 + pp;
            float g = 1.0f / (1.0f + expf(-(s[pp * 2] + bias0[j])));
            float h = tanhf(s[pp * 2 + 1] + bias1[j]);
            float zb = (1.0f - g) * zn32p[(size_t)b * D_ + j] + g * h;
            out[(size_t)b * 1536 + j] = f2bf(zb);
        }
    } else if (EPI == 3) {
        unsigned short* out = (unsigned short*)outp;
        ushort4 o;
#pragma unroll
        for (int j = 0; j < 4; j++) {
            float pre = s[j] + bias0[col + j];
            float val = 0.5f * pre * (1.0f + erff(pre * 0.70710678118654752f));
            ((unsigned short*)&o)[j] = f2bf(val);
        }
        *(ushort4*)(out + (size_t)b * N + col) = o;
    } else {  // EPI == 4: transposed f32 out[col][b]
        float* out = (float*)outp;
#pragma unroll
        for (int j = 0; j < 4; j++) {
            out[(size_t)(col + j) * 64 + b] = s[j] + bias0[col + j];
        }
    }
}

// ---- phase: LN(o_pre) + LN(z) ----
__device__ __forceinline__ void phase_oln(const TickArgs& ta, unsigned char* smem) {
    int b = blockIdx.x;
    if (b >= 64) return;
    float* red = (float*)smem;
    int tid = threadIdx.x;
    float v[2];
#pragma unroll
    for (int i = 0; i < 2; i++) {
        int e = tid + i * 256;
        v[i] = ta.opre[(size_t)b * E_ + e] + ta.out_proj_b[e];
    }
    int w = tid >> 6, lane = tid & 63;
    float s1 = v[0] + v[1];
    float s2 = v[0] * v[0] + v[1] * v[1];
#pragma unroll
    for (int off = 32; off >= 1; off >>= 1) { s1 += __shfl_xor(s1, off, 64); s2 += __shfl_xor(s2, off, 64); }
    if (lane == 0) { red[w] = s1; red[4 + w] = s2; }
    __syncthreads();
    s1 = red[0] + red[1] + red[2] + red[3];
    s2 = red[4] + red[5] + red[6] + red[7];
    float mean = s1 * (1.0f / 512.0f);
    float var = s2 * (1.0f / 512.0f) - mean * mean;
    float rstd = 1.0f / sqrtf(var + 1e-5f);
#pragma unroll
    for (int i = 0; i < 2; i++) {
        int e = tid + i * 256;
        unsigned short val = f2bf((v[i] - mean) * rstd * ta.o_ln_g[e] + ta.o_ln_b[e]);
        ta.u_bf[(size_t)b * 1536 + D_ + e] = val;
        ta.fused_bf[(size_t)b * 1536 + D_ + e] = val;
    }
    float zl[4];
    float t1 = 0.f, t2 = 0.f;
#pragma unroll
    for (int i = 0; i < 4; i++) {
        int d = tid + i * 256;
        zl[i] = ta.zbuf[(size_t)b * D_ + d];
        t1 += zl[i]; t2 += zl[i] * zl[i];
    }
#pragma unroll
    for (int off = 32; off >= 1; off >>= 1) { t1 += __shfl_xor(t1, off, 64); t2 += __shfl_xor(t2, off, 64); }
    __syncthreads();
    if (lane == 0) { red[8 + w] = t1; red[12 + w] = t2; }
    __syncthreads();
    t1 = red[8] + red[9] + red[10] + red[11];
    t2 = red[12] + red[13] + red[14] + red[15];
    float zmean = t1 * (1.0f / 1024.0f);
    float zvar = t2 * (1.0f / 1024.0f) - zmean * zmean;
    float zr = 1.0f / sqrtf(zvar + 1e-5f);
#pragma unroll
    for (int i = 0; i < 4; i++) {
        int d = tid + i * 256;
        float zn = (zl[i] - zmean) * zr * ta.z_ln_g[d] + ta.z_ln_b[d];
        ta.u_bf[(size_t)b * 1536 + d] = f2bf(zn);
        ta.zn32[(size_t)b * D_ + d] = zn;
    }
}

// ---- phase: NLM ----
template <int NT>
__device__ __forceinline__ void phase_nlm(const TickArgs& ta, unsigned char* smem) {
    int vb = blockIdx.x;
    if (vb >= 256) return;
    float (*w1s)[2048] = (float(*)[2048])smem;                 // 32KB
    float (*b1s)[128] = (float(*)[128])(smem + 32768);         // 2KB
    float (*w2s)[128] = (float(*)[128])(smem + 34816);         // 2KB
    float (*b2s)[2] = (float(*)[2])(smem + 36864);
    int tid = threadIdx.x;
    int w = tid >> 6, lane = tid & 63;
    int d = vb * 4 + w;
    for (int i = lane; i < 2048; i += 64) w1s[w][i] = bf2f(ta.nlm1w_bf[(size_t)d * 2048 + i]);
    for (int i = lane; i < 128; i += 64) {
        b1s[w][i] = ta.nlm1_b[(size_t)d * 128 + i];
        w2s[w][i] = ta.nlm2_w[(size_t)d * 128 + i];
    }
    if (lane < 2) b2s[w][lane] = ta.nlm2_b[d * 2 + lane];
    __syncthreads();
    const int b = lane;
    float av[NT];
#pragma unroll
    for (int s = 0; s < NT; s++) av[s] = ta.AbufT[((size_t)s * D_ + d) * 64 + b];
    constexpr int moff = M_ - NT;
    float o0 = b2s[w][0], o1 = b2s[w][1];
    for (int hh = 0; hh < 64; hh++) {
        float a = b1s[w][hh], bb = b1s[w][hh + 64];
#pragma unroll
        for (int s = 0; s < NT; s++) {
            float x = av[s];
            a += x * w1s[w][(s + moff) * 128 + hh];
            bb += x * w1s[w][(s + moff) * 128 + hh + 64];
        }
        float z1 = a / (1.0f + expf(-bb));
        o0 += z1 * w2s[w][hh * 2];
        o1 += z1 * w2s[w][hh * 2 + 1];
    }
    float zv = o0 / (1.0f + expf(-o1));
    ta.zbuf[(size_t)b * D_ + d] = zv;
    ta.out_zt[((size_t)b * T_ + (NT - 1)) * D_ + d] = zv;
}

// ---- phase: pair-sync + head + certainty ----
__device__ __forceinline__ void phase_synchead(const TickArgs& ta, unsigned char* smem, int t) {
    int b = blockIdx.x;
    if (b >= 64) return;
    float* zv = (float*)smem;          // 1024
    float* red = zv + 1024;            // 16
    int tid = threadIdx.x;
    for (int i = tid; i < D_; i += 256) zv[i] = ta.zbuf[(size_t)b * D_ + i];
    __syncthreads();
    float l0 = 0.f, l1 = 0.f, l2 = 0.f, l3 = 0.f;
    for (int p = tid; p < P_; p += 256) {
        size_t ip = (size_t)b * P_ + p;
        float zl = zv[ta.act_l[p]], zr = zv[ta.act_r[p]];
        float da = 1.0f / (1.0f + expf(ta.raw_a[p]));
        float aa = da * ta.a_a[ip] + zl * zr;
        float ba = da * ta.b_a[ip] + 1.0f;
        ta.a_a[ip] = aa; ta.b_a[ip] = ba;
        ta.s_a_bf[(size_t)b * P_ + p] = f2bf(aa / sqrtf(ba + 1e-8f));
        float zlo = zv[ta.out_l[p]], zro = zv[ta.out_r[p]];
        float dz = 1.0f / (1.0f + expf(ta.raw_o[p]));
        float ao = dz * ta.a_o[ip] + zlo * zro;
        float bo = dz * ta.b_o[ip] + 1.0f;
        ta.a_o[ip] = ao; ta.b_o[ip] = bo;
        float so = ao / sqrtf(bo + 1e-8f);
        l0 += so * ta.head_w[p];
        l1 += so * ta.head_w[P_ + p];
        l2 += so * ta.head_w[2 * P_ + p];
        l3 += so * ta.head_w[3 * P_ + p];
    }
    int w = tid >> 6, lane = tid & 63;
#pragma unroll
    for (int off = 32; off >= 1; off >>= 1) {
        l0 += __shfl_xor(l0, off, 64);
        l1 += __shfl_xor(l1, off, 64);
        l2 += __shfl_xor(l2, off, 64);
        l3 += __shfl_xor(l3, off, 64);
    }
    if (lane == 0) { red[w * 4 + 0] = l0; red[w * 4 + 1] = l1; red[w * 4 + 2] = l2; red[w * 4 + 3] = l3; }
    __syncthreads();
    if (tid == 0) {
        float lg[4];
#pragma unroll
        for (int c = 0; c < 4; c++) {
            lg[c] = red[c] + red[4 + c] + red[8 + c] + red[12 + c] + ta.head_b[c];
            ta.out_logits[((size_t)b * C_ + c) * T_ + t] = lg[c];
        }
        float m = fmaxf(fmaxf(lg[0], lg[1]), fmaxf(lg[2], lg[3]));
        float e0 = expf(lg[0] - m), e1 = expf(lg[1] - m), e2 = expf(lg[2] - m), e3 = expf(lg[3] - m);
        float inv = 1.0f / (e0 + e1 + e2 + e3);
        float ent = 0.f, pp;
        pp = fmaxf(e0 * inv, 1e-8f); ent -= pp * logf(pp);
        pp = fmaxf(e1 * inv, 1e-8f); ent -= pp * logf(pp);
        pp = fmaxf(e2 * inv, 1e-8f); ent -= pp * logf(pp);
        pp = fmaxf(e3 * inv, 1e-8f); ent -= pp * logf(pp);
        ta.out_cert[(size_t)b * T_ + t] = 1.0f - ent * (1.0f / 1.3862943611198906f);
    }
}

__global__ __launch_bounds__(256, 2) void tick_kernel(TickArgs ta) {
    __shared__ __align__(16) unsigned char smem[40960];
    for (int t = 0; t < T_; t++) {
        phase_qh_attn(ta, smem);
        grid_barrier(ta.bar);
        phase_gemmNK<1>(ta.o_bf, ta.Wout_bf, nullptr, nullptr, nullptr, ta.opre, 512, 512, smem, 32);
        grid_barrier(ta.bar);
        phase_oln(ta, smem);
        grid_barrier(ta.bar);
        phase_gemmNK<2>(ta.u_bf, ta.Wgc_bf, ta.gate_b, ta.cand_b, ta.zn32, ta.fused_bf, 2048, 1536, smem, 128);
        grid_barrier(ta.bar);
        phase_gemmNK<3>(ta.fused_bf, ta.Ws1_bf, ta.syn1_b, nullptr, nullptr, ta.tbuf_bf, 2048, 1536, smem, 128);
        grid_barrier(ta.bar);
        phase_gemmNK<4>(ta.tbuf_bf, ta.Ws2_bf, ta.syn2_b, nullptr, nullptr,
                        ta.AbufT + (size_t)t * D_ * 64, 1024, 2048, smem, 64);
        grid_barrier(ta.bar);
        switch (t) {
            case 0:  phase_nlm<1>(ta, smem); break;
            case 1:  phase_nlm<2>(ta, smem); break;
            case 2:  phase_nlm<3>(ta, smem); break;
            case 3:  phase_nlm<4>(ta, smem); break;
            case 4:  phase_nlm<5>(ta, smem); break;
            case 5:  phase_nlm<6>(ta, smem); break;
            case 6:  phase_nlm<7>(ta, smem); break;
            case 7:  phase_nlm<8>(ta, smem); break;
            case 8:  phase_nlm<9>(ta, smem); break;
            case 9:  phase_nlm<10>(ta, smem); break;
            case 10: phase_nlm<11>(ta, smem); break;
            default: phase_nlm<12>(ta, smem); break;
        }
        grid_barrier(ta.bar);
        phase_synchead(ta, smem, t);
        grid_barrier(ta.bar);
    }
}

extern "C" void kernel_launch(void* const* d_in, const int* in_sizes, int n_in,
                              void* d_out, int out_size, void* d_ws, size_t ws_size,
                              hipStream_t stream) {
    const float* kv_tokens  = (const float*)d_in[0];
    const float* raw_r_act  = (const float*)d_in[1];
    const float* raw_r_out  = (const float*)d_in[2];
    const float* q_w        = (const float*)d_in[3];
    const float* q_b        = (const float*)d_in[4];
    const float* in_proj_w  = (const float*)d_in[5];
    const float* in_proj_b  = (const float*)d_in[6];
    const float* out_proj_w = (const float*)d_in[7];
    const float* out_proj_b = (const float*)d_in[8];
    const float* z_ln_g     = (const float*)d_in[9];
    const float* z_ln_b     = (const float*)d_in[10];
    const float* o_ln_g     = (const float*)d_in[11];
    const float* o_ln_b     = (const float*)d_in[12];
    const float* gate_w     = (const float*)d_in[13];
    const float* gate_b     = (const float*)d_in[14];
    const float* cand_w     = (const float*)d_in[15];
    const float* cand_b     = (const float*)d_in[16];
    const float* syn1_w     = (const float*)d_in[17];
    const float* syn1_b     = (const float*)d_in[18];
    const float* syn2_w     = (const float*)d_in[19];
    const float* syn2_b     = (const float*)d_in[20];
    const float* nlm1_w     = (const float*)d_in[21];
    const float* nlm1_b     = (const float*)d_in[22];
    const float* nlm2_w     = (const float*)d_in[23];
    const float* nlm2_b     = (const float*)d_in[24];
    const float* head_w     = (const float*)d_in[25];
    const float* head_b     = (const float*)d_in[26];
    const int* act_l        = (const int*)d_in[27];
    const int* act_r        = (const int*)d_in[28];
    const int* out_l        = (const int*)d_in[29];
    const int* out_r        = (const int*)d_in[30];

    float* out = (float*)d_out;
    float* out_logits = out;                       // [B,C,T]
    float* out_cert = out + B_ * C_ * T_;          // [B,T]
    float* out_zt = out_cert + B_ * T_;            // [B,T,D]

    char* ws = (char*)d_ws;
    size_t off = 0;
    auto alloc = [&](size_t bytes) { void* p = ws + off; off += (bytes + 255) & ~(size_t)255; return p; };
    unsigned short* kvbuf   = (unsigned short*)alloc((size_t)B_ * N_ * 1024 * 2);   // 128MB
    unsigned short* kv_bf   = (unsigned short*)alloc((size_t)B_ * N_ * E_ * 2);     // 64MB
    unsigned short* Wkv_bf  = (unsigned short*)alloc((size_t)1024 * E_ * 2);
    unsigned short* Wq_bf   = (unsigned short*)alloc((size_t)E_ * E_ * 2);
    unsigned short* qwT_bf  = (unsigned short*)alloc((size_t)P_ * E_ * 2);
    unsigned short* Wc_bf   = (unsigned short*)alloc((size_t)E_ * P_ * 2);
    unsigned short* Wgc_bf  = (unsigned short*)alloc((size_t)2048 * 1536 * 2);
    unsigned short* Ws1_bf  = (unsigned short*)alloc((size_t)2048 * 1536 * 2);
    unsigned short* Ws2_bf  = (unsigned short*)alloc((size_t)1024 * 2048 * 2);
    unsigned short* Wout_bf = (unsigned short*)alloc((size_t)E_ * E_ * 2);
    unsigned short* nlm1w_bf= (unsigned short*)alloc((size_t)1024 * 2048 * 2);
    float* b_comb = (float*)alloc(E_ * 4);
    unsigned short* s_a_bf  = (unsigned short*)alloc((size_t)B_ * P_ * 2);
    unsigned short* o_bf    = (unsigned short*)alloc((size_t)B_ * E_ * 2);
    unsigned short* u_bf    = (unsigned short*)alloc((size_t)B_ * 1536 * 2);
    unsigned short* fused_bf= (unsigned short*)alloc((size_t)B_ * 1536 * 2);
    unsigned short* tbuf_bf = (unsigned short*)alloc((size_t)B_ * HS_ * 2);
    float* opre = (float*)alloc((size_t)B_ * E_ * 4);
    float* zn32 = (float*)alloc((size_t)B_ * D_ * 4);
    float* a_a  = (float*)alloc((size_t)B_ * P_ * 4);
    float* b_a  = (float*)alloc((size_t)B_ * P_ * 4);
    float* a_o  = (float*)alloc((size_t)B_ * P_ * 4);
    float* b_o  = (float*)alloc((size_t)B_ * P_ * 4);
    float* zbuf = (float*)alloc((size_t)B_ * D_ * 4);
    float* AbufT = (float*)alloc((size_t)T_ * D_ * B_ * 4);
    unsigned int* bar = (unsigned int*)alloc(256);

    init_kernel<<<512, 256, 0, stream>>>(s_a_bf, a_a, b_a, a_o, b_o, zbuf, bar);

    // --- one-time weight prep ---
    cvt_bf16_kernel<<<(1024 * E_ / 4 + 255) / 256, 256, 0, stream>>>(in_proj_w + (size_t)E_ * E_, Wkv_bf, 1024 * E_ / 4);
    cvt_bf16_kernel<<<(E_ * E_ / 4 + 255) / 256, 256, 0, stream>>>(in_proj_w, Wq_bf, E_ * E_ / 4);
    cvt_ilv_kernel<<<2048, 256, 0, stream>>>(gate_w, cand_w, Wgc_bf);
    cvt_bf16_kernel<<<(2048 * 1536 / 4 + 255) / 256, 256, 0, stream>>>(syn1_w, Ws1_bf, 2048 * 1536 / 4);
    cvt_bf16_kernel<<<(1024 * 2048 / 4 + 255) / 256, 256, 0, stream>>>(syn2_w, Ws2_bf, 1024 * 2048 / 4);
    cvt_bf16_kernel<<<(E_ * E_ / 4 + 255) / 256, 256, 0, stream>>>(out_proj_w, Wout_bf, E_ * E_ / 4);
    cvt_bf16_kernel<<<(1024 * 2048 / 4 + 255) / 256, 256, 0, stream>>>(nlm1_w, nlm1w_bf, 1024 * 2048 / 4);
    transpose_cvt_kernel<<<dim3(P_ / 32, E_ / 32), 256, 0, stream>>>(q_w, qwT_bf, E_, P_);
    bcomb_kernel<<<2, 256, 0, stream>>>(in_proj_w, in_proj_b, q_b, b_comb);
    gemm_bt_kernel<false><<<dim3(P_ / 128, E_ / 128), 256, 0, stream>>>(Wq_bf, qwT_bf, nullptr, Wc_bf, E_, P_, E_);

    // --- KV projection ---
    cvt_bf16_kernel<<<(B_ * N_ * E_ / 4) / 256, 256, 0, stream>>>(kv_tokens, kv_bf, B_ * N_ * E_ / 4);
    gemm_bt_kernel<true><<<dim3(8, 512), 256, 0, stream>>>(kv_bf, Wkv_bf, in_proj_b + E_,
                                                           kvbuf, B_ * N_, 1024, E_);

    // --- all 12 ticks in one persistent kernel ---
    TickArgs ta;
    ta.kvbuf = kvbuf; ta.Wc_bf = Wc_bf; ta.b_comb = b_comb;
    ta.Wout_bf = Wout_bf; ta.out_proj_b = out_proj_b;
    ta.o_ln_g = o_ln_g; ta.o_ln_b = o_ln_b; ta.z_ln_g = z_ln_g; ta.z_ln_b = z_ln_b;
    ta.Wgc_bf = Wgc_bf; ta.gate_b = gate_b; ta.cand_b = cand_b;
    ta.Ws1_bf = Ws1_bf; ta.syn1_b = syn1_b; ta.Ws2_bf = Ws2_bf; ta.syn2_b = syn2_b;
    ta.nlm1w_bf = nlm1w_bf; ta.nlm1_b = nlm1_b; ta.nlm2_w = nlm2_w; ta.nlm2_b = nlm2_b;
    ta.head_w = head_w; ta.head_b = head_b;
    ta.act_l = act_l; ta.act_r = act_r; ta.out_l = out_l; ta.out_r = out_r;
    ta.raw_a = raw_r_act; ta.raw_o = raw_r_out;
    ta.s_a_bf = s_a_bf; ta.o_bf = o_bf; ta.opre = opre; ta.u_bf = u_bf;
    ta.fused_bf = fused_bf; ta.zn32 = zn32; ta.tbuf_bf = tbuf_bf; ta.AbufT = AbufT;
    ta.zbuf = zbuf; ta.a_a = a_a; ta.b_a = b_a; ta.a_o = a_o; ta.b_o = b_o;
    ta.out_logits = out_logits; ta.out_cert = out_cert; ta.out_zt = out_zt;
    ta.bar = bar;
    tick_kernel<<<dim3(NBLK_), dim3(256), 0, stream>>>(ta);
}

// Round 6
// 1748.556 us; speedup vs baseline: 8.4637x; 8.4637x over previous
//
#include <hip/hip_runtime.h>
#include <hip/hip_bf16.h>

#define B_ 64
#define N_ 1024
#define E_ 512
#define D_ 1024
#define M_ 16
#define T_ 12
#define P_ 2048
#define HS_ 2048
#define HN_ 64
#define C_ 4
#define NH_ 8
#define DH_ 64

typedef __attribute__((ext_vector_type(8))) short bf16x8;
typedef __attribute__((ext_vector_type(4))) float f32x4;

__device__ __forceinline__ float bf2f(unsigned int u) {
    union { unsigned int i; float f; } c; c.i = (u & 0xffffu) << 16; return c.f;
}
__device__ __forceinline__ unsigned short f2bf(float f) {
    union { float f; unsigned int i; } c; c.f = f;
    unsigned int x = c.i;
    unsigned int r = x + 0x7fffu + ((x >> 16) & 1u);
    return (unsigned short)(r >> 16);
}
__device__ __forceinline__ float dot2bf(unsigned int a, unsigned int b) {
    union { unsigned int i; float f; } al, ah, bl, bh;
    al.i = a << 16; ah.i = a & 0xffff0000u;
    bl.i = b << 16; bh.i = b & 0xffff0000u;
    return al.f * bl.f + ah.f * bh.f;
}

// ---------------- init state ----------------
__global__ void init_kernel(unsigned short* s_a_bf, float* a_a, float* b_a, float* a_o, float* b_o, float* z) {
    int i = blockIdx.x * 256 + threadIdx.x;
    if (i < B_ * P_) { a_a[i] = 0.f; b_a[i] = 1.f; a_o[i] = 0.f; b_o[i] = 1.f; s_a_bf[i] = 0; }
    if (i < B_ * D_) z[i] = 0.f;
}

// ---------------- f32 -> bf16 conversion ----------------
__global__ __launch_bounds__(256) void cvt_bf16_kernel(const float* __restrict__ in,
                                                       unsigned short* __restrict__ out, int n4) {
    int i = blockIdx.x * 256 + threadIdx.x;
    if (i < n4) {
        float4 v = ((const float4*)in)[i];
        ushort4 o;
        o.x = f2bf(v.x); o.y = f2bf(v.y); o.z = f2bf(v.z); o.w = f2bf(v.w);
        ((ushort4*)out)[i] = o;
    }
}

// ---------------- interleave gate/cand rows ----------------
__global__ __launch_bounds__(256) void cvt_ilv_kernel(const float* __restrict__ g,
                                                      const float* __restrict__ c,
                                                      unsigned short* __restrict__ out) {
    int r = blockIdx.x;  // 0..2047
    const float* src = (r & 1) ? (c + (size_t)(r >> 1) * 1536) : (g + (size_t)(r >> 1) * 1536);
    for (int k = threadIdx.x * 4; k < 1536; k += 1024) {
        float4 v = *(const float4*)(src + k);
        ushort4 o;
        o.x = f2bf(v.x); o.y = f2bf(v.y); o.z = f2bf(v.z); o.w = f2bf(v.w);
        *(ushort4*)(out + (size_t)r * 1536 + k) = o;
    }
}

// ---------------- transpose + cvt: out[c][r] = bf16(in[r][c]) ----------------
__global__ __launch_bounds__(256) void transpose_cvt_kernel(const float* __restrict__ in,
                                                            unsigned short* __restrict__ out,
                                                            int R, int Ccols) {
    __shared__ float tb[32][33];
    int c0 = blockIdx.x * 32, r0 = blockIdx.y * 32;
    int tx = threadIdx.x & 31, ty = threadIdx.x >> 5;
#pragma unroll
    for (int i = 0; i < 32; i += 8) tb[ty + i][tx] = in[(size_t)(r0 + ty + i) * Ccols + c0 + tx];
    __syncthreads();
#pragma unroll
    for (int i = 0; i < 32; i += 8) out[(size_t)(c0 + ty + i) * R + r0 + tx] = f2bf(tb[tx][ty + i]);
}

// ---------------- combined query bias ----------------
__global__ __launch_bounds__(256) void bcomb_kernel(const float* __restrict__ in_proj_w,
                                                    const float* __restrict__ in_proj_b,
                                                    const float* __restrict__ q_b,
                                                    float* __restrict__ bc) {
    int e = blockIdx.x * 256 + threadIdx.x;
    if (e < E_) {
        const float* wr = in_proj_w + (size_t)e * E_;
        float s = in_proj_b[e];
        for (int k = 0; k < E_; k += 4) {
            float4 w4 = *(const float4*)(wr + k);
            float4 q4 = *(const float4*)(q_b + k);
            s += w4.x * q4.x + w4.y * q4.y + w4.z * q4.z + w4.w * q4.w;
        }
        bc[e] = s;
    }
}

// ---------------- big bf16 MFMA GEMM (128x128 tile), uniform-spread swizzle + XCD swizzle ----------------
template <bool HAS_BIAS>
__global__ __launch_bounds__(256) void gemm_bt_kernel(const unsigned short* __restrict__ A,
                                                      const unsigned short* __restrict__ Bt,
                                                      const float* __restrict__ bias,
                                                      unsigned short* __restrict__ C,
                                                      int M, int N, int K) {
    __shared__ __align__(16) unsigned short ldsA[2][4096];
    __shared__ __align__(16) unsigned short ldsB[2][4096];
    int id = blockIdx.y * gridDim.x + blockIdx.x;
    int nwg = gridDim.x * gridDim.y;
    int swz = (id & 7) * (nwg >> 3) + (id >> 3);
    int bx = swz % gridDim.x, by = swz / gridDim.x;
    int m0 = by * 128;
    int n0 = bx * 128;
    int tid = threadIdx.x;
    int wv = tid >> 6, l = tid & 63;
    int wr = wv >> 1, wc = wv & 1;
    int lr = l & 15, lg = l >> 4;
    f32x4 acc[4][4] = {};

    auto stage = [&](int buf, int kt) {
        int k0 = kt * 32;
#pragma unroll
        for (int i = 0; i < 2; i++) {
            int tsk = tid + 256 * i;
            int r = tsk >> 2, g = tsk & 3;
            int gs = (g ^ (r & 3) ^ ((r >> 2) & 3)) * 8;
            __builtin_amdgcn_global_load_lds(
                (const __attribute__((address_space(1))) void*)(A + (size_t)(m0 + r) * K + k0 + gs),
                (__attribute__((address_space(3))) void*)&ldsA[buf][tsk * 8], 16, 0, 0);
        }
#pragma unroll
        for (int i = 0; i < 2; i++) {
            int tsk = tid + 256 * i;
            int r = tsk >> 2, g = tsk & 3;
            int gs = (g ^ (r & 3) ^ ((r >> 2) & 3)) * 8;
            __builtin_amdgcn_global_load_lds(
                (const __attribute__((address_space(1))) void*)(Bt + (size_t)(n0 + r) * K + k0 + gs),
                (__attribute__((address_space(3))) void*)&ldsB[buf][tsk * 8], 16, 0, 0);
        }
    };

    int nt = K >> 5;
    stage(0, 0);
    for (int t = 0; t < nt; t++) {
        int cur = t & 1;
        if (t + 1 < nt) {
            stage(cur ^ 1, t + 1);
            asm volatile("s_waitcnt vmcnt(4)" ::: "memory");
        } else {
            asm volatile("s_waitcnt vmcnt(0)" ::: "memory");
        }
        __builtin_amdgcn_s_barrier();
        bf16x8 af[4], bfr[4];
#pragma unroll
        for (int mi = 0; mi < 4; mi++) {
            int r = wr * 64 + mi * 16 + lr;
            int slot = lg ^ (r & 3) ^ ((r >> 2) & 3);
            af[mi] = *(const bf16x8*)&ldsA[cur][r * 32 + (slot << 3)];
        }
#pragma unroll
        for (int ni = 0; ni < 4; ni++) {
            int c = wc * 64 + ni * 16 + lr;
            int slot = lg ^ (c & 3) ^ ((c >> 2) & 3);
            bfr[ni] = *(const bf16x8*)&ldsB[cur][c * 32 + (slot << 3)];
        }
#pragma unroll
        for (int mi = 0; mi < 4; mi++)
#pragma unroll
            for (int ni = 0; ni < 4; ni++)
                acc[mi][ni] = __builtin_amdgcn_mfma_f32_16x16x32_bf16(af[mi], bfr[ni], acc[mi][ni], 0, 0, 0);
        __builtin_amdgcn_s_barrier();
    }
#pragma unroll
    for (int ni = 0; ni < 4; ni++) {
        int col = n0 + wc * 64 + ni * 16 + lr;
        float bv = HAS_BIAS ? bias[col] : 0.0f;
#pragma unroll
        for (int mi = 0; mi < 4; mi++) {
            int row = m0 + wr * 64 + mi * 16 + lg * 4;
#pragma unroll
            for (int r = 0; r < 4; r++) {
                C[(size_t)(row + r) * N + col] = f2bf(acc[mi][ni][r] + bv);
            }
        }
    }
}

// ---------------- fused batch-64 GEMM: 64x16 tile, 4-wave K-split, in-block reduce + epilogue ----------------
// EPI 2: gate/cand interleaved -> z_bar. 3: gelu -> bf16. 4: f32 +bias -> transposed [col][b].
template <int EPI>
__global__ __launch_bounds__(256) void gemmNK_kernel(const unsigned short* __restrict__ A,
                                                     const unsigned short* __restrict__ W,
                                                     const float* __restrict__ bias0,
                                                     const float* __restrict__ bias1,
                                                     const float* __restrict__ zn32,
                                                     void* __restrict__ outp,
                                                     int N, int K) {
    __shared__ __align__(16) unsigned short ldsA[4][2][2048];
    __shared__ __align__(16) unsigned short ldsB[4][2][512];
    int n0 = blockIdx.x * 16;
    int tid = threadIdx.x;
    int w = tid >> 6, l = tid & 63;
    int Kw = K >> 2;
    int kb = w * Kw;
    int lr = l & 15, lg = l >> 4;
    int ar = l >> 2, ag = l & 3;
    f32x4 acc[4] = {};

    auto stage = [&](int buf, int kt) {
        int k0 = kb + (kt << 5);
#pragma unroll
        for (int i = 0; i < 4; i++) {
            int row = i * 16 + ar;
            int gs = (ag ^ (row & 3) ^ ((row >> 2) & 3)) << 3;
            __builtin_amdgcn_global_load_lds(
                (const __attribute__((address_space(1))) void*)(A + (size_t)row * K + k0 + gs),
                (__attribute__((address_space(3))) void*)&ldsA[w][buf][i * 512 + l * 8], 16, 0, 0);
        }
        {
            int col = ar;
            int gs = (ag ^ (col & 3) ^ ((col >> 2) & 3)) << 3;
            __builtin_amdgcn_global_load_lds(
                (const __attribute__((address_space(1))) void*)(W + (size_t)(n0 + col) * K + k0 + gs),
                (__attribute__((address_space(3))) void*)&ldsB[w][buf][l * 8], 16, 0, 0);
        }
    };

    int nt = Kw >> 5;
    stage(0, 0);
    for (int t = 0; t < nt; t++) {
        int cur = t & 1;
        if (t + 1 < nt) {
            stage(cur ^ 1, t + 1);
            asm volatile("s_waitcnt vmcnt(5)" ::: "memory");
        } else {
            asm volatile("s_waitcnt vmcnt(0)" ::: "memory");
        }
        int bslot = lg ^ (lr & 3) ^ ((lr >> 2) & 3);
        bf16x8 bf = *(const bf16x8*)&ldsB[w][cur][lr * 32 + (bslot << 3)];
#pragma unroll
        for (int mi = 0; mi < 4; mi++) {
            int rr = mi * 16 + lr;
            int slot = lg ^ (rr & 3) ^ ((rr >> 2) & 3);
            bf16x8 af = *(const bf16x8*)&ldsA[w][cur][rr * 32 + (slot << 3)];
            acc[mi] = __builtin_amdgcn_mfma_f32_16x16x32_bf16(af, bf, acc[mi], 0, 0, 0);
        }
    }
    __syncthreads();
    float* red = (float*)&ldsA[0][0][0];  // [4][64][16]
#pragma unroll
    for (int mi = 0; mi < 4; mi++) {
        int row = mi * 16 + lg * 4;
#pragma unroll
        for (int q = 0; q < 4; q++) red[w * 1024 + (row + q) * 16 + lr] = acc[mi][q];
    }
    __syncthreads();
    int b = tid >> 2, c4 = (tid & 3) << 2;
    f32x4 s = *(f32x4*)&red[b * 16 + c4];
#pragma unroll
    for (int ww = 1; ww < 4; ww++) {
        f32x4 v = *(f32x4*)&red[ww * 1024 + b * 16 + c4];
        s[0] += v[0]; s[1] += v[1]; s[2] += v[2]; s[3] += v[3];
    }
    int col = n0 + c4;
    if (EPI == 2) {
        unsigned short* out = (unsigned short*)outp;
        int j0 = col >> 1;
#pragma unroll
        for (int pp = 0; pp < 2; pp++) {
            int j = j0 + pp;
            float g = 1.0f / (1.0f + expf(-(s[pp * 2] + bias0[j])));
            float h = tanhf(s[pp * 2 + 1] + bias1[j]);
            float zb = (1.0f - g) * zn32[(size_t)b * D_ + j] + g * h;
            out[(size_t)b * 1536 + j] = f2bf(zb);
        }
    } else if (EPI == 3) {
        unsigned short* out = (unsigned short*)outp;
        ushort4 o;
#pragma unroll
        for (int j = 0; j < 4; j++) {
            float pre = s[j] + bias0[col + j];
            float val = 0.5f * pre * (1.0f + erff(pre * 0.70710678118654752f));
            ((unsigned short*)&o)[j] = f2bf(val);
        }
        *(ushort4*)(out + (size_t)b * N + col) = o;
    } else {  // EPI == 4: transposed f32 out[col][b]
        float* out = (float*)outp;
#pragma unroll
        for (int j = 0; j < 4; j++) {
            out[(size_t)(col + j) * 64 + b] = s[j] + bias0[col + j];
        }
    }
}

// ---------------- attention for one (b,h) with fused qh ----------------
__global__ __launch_bounds__(256) void attn_kernel(const unsigned short* __restrict__ kvbuf,
                                                   const unsigned short* __restrict__ s_a_bf,
                                                   const unsigned short* __restrict__ Wc_bf,
                                                   const float* __restrict__ b_comb,
                                                   unsigned short* __restrict__ o_bf) {
    int bh = blockIdx.x;
    int b = bh >> 3, h = bh & 7;
    __shared__ float sc[N_];
    __shared__ float qv[DH_];
    __shared__ float red[8];
    __shared__ float opart[4][DH_];
    int tid = threadIdx.x;
    int w = tid >> 6, lane = tid & 63;
    // ---- qh for this head: q[col] = s_a[b,:] . Wc[h*64+col,:] + b_comb ----
    uint4 sa[4];
#pragma unroll
    for (int i = 0; i < 4; i++)
        sa[i] = *(const uint4*)(s_a_bf + (size_t)b * P_ + i * 512 + lane * 8);
    for (int cg = 0; cg < 16; cg++) {
        int col = cg * 4 + w;
        const unsigned short* wr = Wc_bf + (size_t)(h * 64 + col) * P_;
        float acc = 0.f;
#pragma unroll
        for (int i = 0; i < 4; i++) {
            uint4 wv = *(const uint4*)(wr + i * 512 + lane * 8);
            acc += dot2bf(wv.x, sa[i].x) + dot2bf(wv.y, sa[i].y)
                 + dot2bf(wv.z, sa[i].z) + dot2bf(wv.w, sa[i].w);
        }
#pragma unroll
        for (int off = 32; off >= 1; off >>= 1) acc += __shfl_xor(acc, off, 64);
        if (lane == 0) qv[col] = acc + b_comb[h * 64 + col];
    }
    __syncthreads();
    // ---- scores ----
    const unsigned short* kb = kvbuf + (size_t)b * N_ * 1024 + h * DH_;
    float myv[4];
#pragma unroll
    for (int i = 0; i < 4; i++) {
        int n = tid + i * 256;
        const unsigned short* kr = kb + (size_t)n * 1024;
        float s = 0.f;
#pragma unroll
        for (int d = 0; d < DH_; d += 8) {
            uint4 pk = *(const uint4*)(kr + d);
            s += bf2f(pk.x) * qv[d + 0] + bf2f(pk.x >> 16) * qv[d + 1]
               + bf2f(pk.y) * qv[d + 2] + bf2f(pk.y >> 16) * qv[d + 3]
               + bf2f(pk.z) * qv[d + 4] + bf2f(pk.z >> 16) * qv[d + 5]
               + bf2f(pk.w) * qv[d + 6] + bf2f(pk.w >> 16) * qv[d + 7];
        }
        myv[i] = s * 0.125f;
    }
    float m = fmaxf(fmaxf(myv[0], myv[1]), fmaxf(myv[2], myv[3]));
#pragma unroll
    for (int off = 32; off >= 1; off >>= 1) m = fmaxf(m, __shfl_xor(m, off, 64));
    if (lane == 0) red[w] = m;
    __syncthreads();
    m = fmaxf(fmaxf(red[0], red[1]), fmaxf(red[2], red[3]));
    float s = 0.f;
#pragma unroll
    for (int i = 0; i < 4; i++) {
        float e = expf(myv[i] - m);
        sc[tid + i * 256] = e;
        s += e;
    }
#pragma unroll
    for (int off = 32; off >= 1; off >>= 1) s += __shfl_xor(s, off, 64);
    if (lane == 0) red[4 + w] = s;
    __syncthreads();
    float inv = 1.0f / (red[4] + red[5] + red[6] + red[7]);
    // ---- V pass ----
    const unsigned short* vbp = kvbuf + (size_t)b * N_ * 1024 + E_ + h * DH_;
    int ng = lane >> 4, d4 = (lane & 15) << 2;
    float a0 = 0.f, a1 = 0.f, a2 = 0.f, a3 = 0.f;
    int n0 = w * 256;
    for (int i = 0; i < 64; i++) {
        int n = n0 + i * 4 + ng;
        uint2 pv = *(const uint2*)(vbp + (size_t)n * 1024 + d4);
        float sv = sc[n];
        a0 += sv * bf2f(pv.x);
        a1 += sv * bf2f(pv.x >> 16);
        a2 += sv * bf2f(pv.y);
        a3 += sv * bf2f(pv.y >> 16);
    }
    a0 += __shfl_xor(a0, 16, 64); a0 += __shfl_xor(a0, 32, 64);
    a1 += __shfl_xor(a1, 16, 64); a1 += __shfl_xor(a1, 32, 64);
    a2 += __shfl_xor(a2, 16, 64); a2 += __shfl_xor(a2, 32, 64);
    a3 += __shfl_xor(a3, 16, 64); a3 += __shfl_xor(a3, 32, 64);
    if (lane < 16) {
        opart[w][d4 + 0] = a0;
        opart[w][d4 + 1] = a1;
        opart[w][d4 + 2] = a2;
        opart[w][d4 + 3] = a3;
    }
    __syncthreads();
    if (tid < DH_) {
        float r = (opart[0][tid] + opart[1][tid] + opart[2][tid] + opart[3][tid]) * inv;
        o_bf[(size_t)b * E_ + h * DH_ + tid] = f2bf(r);
    }
}

// ---------------- fused oproj (transposed weights, coalesced) + LN(o) + LN(z) ----------------
__global__ __launch_bounds__(256) void oproj_oln_kernel(const unsigned short* __restrict__ o_bf,
                                                        const unsigned short* __restrict__ WoutT_bf,
                                                        const float* __restrict__ bout,
                                                        const float* __restrict__ og,
                                                        const float* __restrict__ obv,
                                                        const float* __restrict__ z,
                                                        const float* __restrict__ zg,
                                                        const float* __restrict__ zbv,
                                                        unsigned short* __restrict__ u_bf,
                                                        unsigned short* __restrict__ fused_bf,
                                                        float* __restrict__ zn32) {
    int b = blockIdx.x, tid = threadIdx.x;
    __shared__ float ov[E_];
    __shared__ float red[16];
    {
        unsigned int pk = *(const unsigned int*)(o_bf + (size_t)b * E_ + tid * 2);
        ov[tid * 2] = bf2f(pk);
        ov[tid * 2 + 1] = bf2f(pk >> 16);
    }
    __syncthreads();
    int e0 = tid * 2;
    float v0 = 0.f, v1 = 0.f;
#pragma unroll 8
    for (int k = 0; k < E_; k++) {
        unsigned int pk = *(const unsigned int*)(WoutT_bf + (size_t)k * E_ + e0);
        float o = ov[k];
        v0 += o * bf2f(pk);
        v1 += o * bf2f(pk >> 16);
    }
    v0 += bout[e0];
    v1 += bout[e0 + 1];
    int w = tid >> 6, lane = tid & 63;
    float s1 = v0 + v1;
    float s2 = v0 * v0 + v1 * v1;
#pragma unroll
    for (int off = 32; off >= 1; off >>= 1) { s1 += __shfl_xor(s1, off, 64); s2 += __shfl_xor(s2, off, 64); }
    if (lane == 0) { red[w] = s1; red[4 + w] = s2; }
    __syncthreads();
    s1 = red[0] + red[1] + red[2] + red[3];
    s2 = red[4] + red[5] + red[6] + red[7];
    float mean = s1 * (1.0f / 512.0f);
    float var = s2 * (1.0f / 512.0f) - mean * mean;
    float rstd = 1.0f / sqrtf(var + 1e-5f);
    {
        unsigned int pk = (unsigned int)f2bf((v0 - mean) * rstd * og[e0] + obv[e0])
                        | ((unsigned int)f2bf((v1 - mean) * rstd * og[e0 + 1] + obv[e0 + 1]) << 16);
        *(unsigned int*)(u_bf + (size_t)b * 1536 + D_ + e0) = pk;
        *(unsigned int*)(fused_bf + (size_t)b * 1536 + D_ + e0) = pk;
    }
    // LN(z)
    float zl[4];
    float t1 = 0.f, t2 = 0.f;
#pragma unroll
    for (int i = 0; i < 4; i++) {
        int d = tid + i * 256;
        zl[i] = z[(size_t)b * D_ + d];
        t1 += zl[i]; t2 += zl[i] * zl[i];
    }
#pragma unroll
    for (int off = 32; off >= 1; off >>= 1) { t1 += __shfl_xor(t1, off, 64); t2 += __shfl_xor(t2, off, 64); }
    __syncthreads();
    if (lane == 0) { red[8 + w] = t1; red[12 + w] = t2; }
    __syncthreads();
    t1 = red[8] + red[9] + red[10] + red[11];
    t2 = red[12] + red[13] + red[14] + red[15];
    float zmean = t1 * (1.0f / 1024.0f);
    float zvar = t2 * (1.0f / 1024.0f) - zmean * zmean;
    float zr = 1.0f / sqrtf(zvar + 1e-5f);
#pragma unroll
    for (int i = 0; i < 4; i++) {
        int d = tid + i * 256;
        float zn = (zl[i] - zmean) * zr * zg[d] + zbv[d];
        u_bf[(size_t)b * 1536 + d] = f2bf(zn);
        zn32[(size_t)b * D_ + d] = zn;
    }
}

// ---------------- NLM over transposed history Abuf_T [t][d][b], bf16 w1 ----------------
template <int NT>
__global__ __launch_bounds__(256) void nlm_kernel(const float* __restrict__ AbufT,
                                                  const unsigned short* __restrict__ w1g_bf,
                                                  const float* __restrict__ b1g,
                                                  const float* __restrict__ w2g,
                                                  const float* __restrict__ b2g,
                                                  float* __restrict__ z,
                                                  float* __restrict__ zt) {
    __shared__ float w1s[4][2048];
    __shared__ float b1s[4][128];
    __shared__ float w2s[4][128];
    __shared__ float b2s[4][2];
    int tid = threadIdx.x;
    int w = tid >> 6, lane = tid & 63;
    int d = blockIdx.x * 4 + w;
    for (int i = lane * 2; i < 2048; i += 128) {
        unsigned int pk = *(const unsigned int*)(w1g_bf + (size_t)d * 2048 + i);
        w1s[w][i] = bf2f(pk);
        w1s[w][i + 1] = bf2f(pk >> 16);
    }
    for (int i = lane; i < 128; i += 64) {
        b1s[w][i] = b1g[(size_t)d * 128 + i];
        w2s[w][i] = w2g[(size_t)d * 128 + i];
    }
    if (lane < 2) b2s[w][lane] = b2g[d * 2 + lane];
    __syncthreads();
    const int b = lane;
    float av[NT];
#pragma unroll
    for (int s = 0; s < NT; s++) av[s] = AbufT[((size_t)s * D_ + d) * 64 + b];
    constexpr int moff = M_ - NT;
    float o0 = b2s[w][0], o1 = b2s[w][1];
    for (int hh = 0; hh < 64; hh++) {
        float a = b1s[w][hh], bb = b1s[w][hh + 64];
#pragma unroll
        for (int s = 0; s < NT; s++) {
            float x = av[s];
            a += x * w1s[w][(s + moff) * 128 + hh];
            bb += x * w1s[w][(s + moff) * 128 + hh + 64];
        }
        float z1 = a / (1.0f + expf(-bb));
        o0 += z1 * w2s[w][hh * 2];
        o1 += z1 * w2s[w][hh * 2 + 1];
    }
    float zv = o0 / (1.0f + expf(-o1));
    z[(size_t)b * D_ + d] = zv;
    zt[((size_t)b * T_ + (NT - 1)) * D_ + d] = zv;
}

// ---------------- pair-sync update + head + certainty ----------------
__global__ __launch_bounds__(256) void synchead_kernel(const float* __restrict__ z,
                                                       const int* __restrict__ act_l, const int* __restrict__ act_r,
                                                       const int* __restrict__ out_l, const int* __restrict__ out_r,
                                                       const float* __restrict__ raw_a, const float* __restrict__ raw_o,
                                                       const float* __restrict__ head_w, const float* __restrict__ head_b,
                                                       float* __restrict__ a_a, float* __restrict__ b_a,
                                                       unsigned short* __restrict__ s_a_bf,
                                                       float* __restrict__ a_o, float* __restrict__ b_o,
                                                       float* __restrict__ out_logits, float* __restrict__ out_cert, int t) {
    int b = blockIdx.x, tid = threadIdx.x;
    __shared__ float zv[D_];
    __shared__ float red[4][4];
    for (int i = tid; i < D_; i += 256) zv[i] = z[(size_t)b * D_ + i];
    __syncthreads();
    float l0 = 0.f, l1 = 0.f, l2 = 0.f, l3 = 0.f;
    for (int p = tid; p < P_; p += 256) {
        size_t ip = (size_t)b * P_ + p;
        float zl = zv[act_l[p]], zr = zv[act_r[p]];
        float da = 1.0f / (1.0f + expf(raw_a[p]));
        float aa = da * a_a[ip] + zl * zr;
        float ba = da * b_a[ip] + 1.0f;
        a_a[ip] = aa; b_a[ip] = ba;
        s_a_bf[(size_t)b * P_ + p] = f2bf(aa / sqrtf(ba + 1e-8f));
        float zlo = zv[out_l[p]], zro = zv[out_r[p]];
        float dz = 1.0f / (1.0f + expf(raw_o[p]));
        float ao = dz * a_o[ip] + zlo * zro;
        float bo = dz * b_o[ip] + 1.0f;
        a_o[ip] = ao; b_o[ip] = bo;
        float so = ao / sqrtf(bo + 1e-8f);
        l0 += so * head_w[p];
        l1 += so * head_w[P_ + p];
        l2 += so * head_w[2 * P_ + p];
        l3 += so * head_w[3 * P_ + p];
    }
    int w = tid >> 6, lane = tid & 63;
#pragma unroll
    for (int off = 32; off >= 1; off >>= 1) {
        l0 += __shfl_xor(l0, off, 64);
        l1 += __shfl_xor(l1, off, 64);
        l2 += __shfl_xor(l2, off, 64);
        l3 += __shfl_xor(l3, off, 64);
    }
    if (lane == 0) { red[w][0] = l0; red[w][1] = l1; red[w][2] = l2; red[w][3] = l3; }
    __syncthreads();
    if (tid == 0) {
        float lg[4];
#pragma unroll
        for (int c = 0; c < 4; c++) {
            lg[c] = red[0][c] + red[1][c] + red[2][c] + red[3][c] + head_b[c];
            out_logits[((size_t)b * C_ + c) * T_ + t] = lg[c];
        }
        float m = fmaxf(fmaxf(lg[0], lg[1]), fmaxf(lg[2], lg[3]));
        float e0 = expf(lg[0] - m), e1 = expf(lg[1] - m), e2 = expf(lg[2] - m), e3 = expf(lg[3] - m);
        float inv = 1.0f / (e0 + e1 + e2 + e3);
        float ent = 0.f, pp;
        pp = fmaxf(e0 * inv, 1e-8f); ent -= pp * logf(pp);
        pp = fmaxf(e1 * inv, 1e-8f); ent -= pp * logf(pp);
        pp = fmaxf(e2 * inv, 1e-8f); ent -= pp * logf(pp);
        pp = fmaxf(e3 * inv, 1e-8f); ent -= pp * logf(pp);
        out_cert[(size_t)b * T_ + t] = 1.0f - ent * (1.0f / 1.3862943611198906f);
    }
}

extern "C" void kernel_launch(void* const* d_in, const int* in_sizes, int n_in,
                              void* d_out, int out_size, void* d_ws, size_t ws_size,
                              hipStream_t stream) {
    const float* kv_tokens  = (const float*)d_in[0];
    const float* raw_r_act  = (const float*)d_in[1];
    const float* raw_r_out  = (const float*)d_in[2];
    const float* q_w        = (const float*)d_in[3];
    const float* q_b        = (const float*)d_in[4];
    const float* in_proj_w  = (const float*)d_in[5];
    const float* in_proj_b  = (const float*)d_in[6];
    const float* out_proj_w = (const float*)d_in[7];
    const float* out_proj_b = (const float*)d_in[8];
    const float* z_ln_g     = (const float*)d_in[9];
    const float* z_ln_b     = (const float*)d_in[10];
    const float* o_ln_g     = (const float*)d_in[11];
    const float* o_ln_b     = (const float*)d_in[12];
    const float* gate_w     = (const float*)d_in[13];
    const float* gate_b     = (const float*)d_in[14];
    const float* cand_w     = (const float*)d_in[15];
    const float* cand_b     = (const float*)d_in[16];
    const float* syn1_w     = (const float*)d_in[17];
    const float* syn1_b     = (const float*)d_in[18];
    const float* syn2_w     = (const float*)d_in[19];
    const float* syn2_b     = (const float*)d_in[20];
    const float* nlm1_w     = (const float*)d_in[21];
    const float* nlm1_b     = (const float*)d_in[22];
    const float* nlm2_w     = (const float*)d_in[23];
    const float* nlm2_b     = (const float*)d_in[24];
    const float* head_w     = (const float*)d_in[25];
    const float* head_b     = (const float*)d_in[26];
    const int* act_l        = (const int*)d_in[27];
    const int* act_r        = (const int*)d_in[28];
    const int* out_l        = (const int*)d_in[29];
    const int* out_r        = (const int*)d_in[30];

    float* out = (float*)d_out;
    float* out_logits = out;                       // [B,C,T]
    float* out_cert = out + B_ * C_ * T_;          // [B,T]
    float* out_zt = out_cert + B_ * T_;            // [B,T,D]

    char* ws = (char*)d_ws;
    size_t off = 0;
    auto alloc = [&](size_t bytes) { void* p = ws + off; off += (bytes + 255) & ~(size_t)255; return p; };
    unsigned short* kvbuf   = (unsigned short*)alloc((size_t)B_ * N_ * 1024 * 2);   // 128MB
    unsigned short* kv_bf   = (unsigned short*)alloc((size_t)B_ * N_ * E_ * 2);     // 64MB
    unsigned short* Wkv_bf  = (unsigned short*)alloc((size_t)1024 * E_ * 2);
    unsigned short* Wq_bf   = (unsigned short*)alloc((size_t)E_ * E_ * 2);
    unsigned short* qwT_bf  = (unsigned short*)alloc((size_t)P_ * E_ * 2);
    unsigned short* Wc_bf   = (unsigned short*)alloc((size_t)E_ * P_ * 2);
    unsigned short* Wgc_bf  = (unsigned short*)alloc((size_t)2048 * 1536 * 2);
    unsigned short* Ws1_bf  = (unsigned short*)alloc((size_t)2048 * 1536 * 2);
    unsigned short* Ws2_bf  = (unsigned short*)alloc((size_t)1024 * 2048 * 2);
    unsigned short* WoutT_bf= (unsigned short*)alloc((size_t)E_ * E_ * 2);
    unsigned short* nlm1w_bf= (unsigned short*)alloc((size_t)1024 * 2048 * 2);
    float* b_comb = (float*)alloc(E_ * 4);
    unsigned short* s_a_bf  = (unsigned short*)alloc((size_t)B_ * P_ * 2);
    unsigned short* o_bf    = (unsigned short*)alloc((size_t)B_ * E_ * 2);
    unsigned short* u_bf    = (unsigned short*)alloc((size_t)B_ * 1536 * 2);
    unsigned short* fused_bf= (unsigned short*)alloc((size_t)B_ * 1536 * 2);
    unsigned short* tbuf_bf = (unsigned short*)alloc((size_t)B_ * HS_ * 2);
    float* zn32 = (float*)alloc((size_t)B_ * D_ * 4);
    float* a_a  = (float*)alloc((size_t)B_ * P_ * 4);
    float* b_a  = (float*)alloc((size_t)B_ * P_ * 4);
    float* a_o  = (float*)alloc((size_t)B_ * P_ * 4);
    float* b_o  = (float*)alloc((size_t)B_ * P_ * 4);
    float* zbuf = (float*)alloc((size_t)B_ * D_ * 4);
    float* AbufT = (float*)alloc((size_t)T_ * D_ * B_ * 4);   // [t][d][b]

    init_kernel<<<512, 256, 0, stream>>>(s_a_bf, a_a, b_a, a_o, b_o, zbuf);

    // --- one-time weight prep ---
    cvt_bf16_kernel<<<(1024 * E_ / 4 + 255) / 256, 256, 0, stream>>>(in_proj_w + (size_t)E_ * E_, Wkv_bf, 1024 * E_ / 4);
    cvt_bf16_kernel<<<(E_ * E_ / 4 + 255) / 256, 256, 0, stream>>>(in_proj_w, Wq_bf, E_ * E_ / 4);
    cvt_ilv_kernel<<<2048, 256, 0, stream>>>(gate_w, cand_w, Wgc_bf);
    cvt_bf16_kernel<<<(2048 * 1536 / 4 + 255) / 256, 256, 0, stream>>>(syn1_w, Ws1_bf, 2048 * 1536 / 4);
    cvt_bf16_kernel<<<(1024 * 2048 / 4 + 255) / 256, 256, 0, stream>>>(syn2_w, Ws2_bf, 1024 * 2048 / 4);
    cvt_bf16_kernel<<<(1024 * 2048 / 4 + 255) / 256, 256, 0, stream>>>(nlm1_w, nlm1w_bf, 1024 * 2048 / 4);
    transpose_cvt_kernel<<<dim3(E_ / 32, E_ / 32), 256, 0, stream>>>(out_proj_w, WoutT_bf, E_, E_);
    transpose_cvt_kernel<<<dim3(P_ / 32, E_ / 32), 256, 0, stream>>>(q_w, qwT_bf, E_, P_);
    bcomb_kernel<<<2, 256, 0, stream>>>(in_proj_w, in_proj_b, q_b, b_comb);
    gemm_bt_kernel<false><<<dim3(P_ / 128, E_ / 128), 256, 0, stream>>>(Wq_bf, qwT_bf, nullptr, Wc_bf, E_, P_, E_);

    // --- KV projection ---
    cvt_bf16_kernel<<<(B_ * N_ * E_ / 4) / 256, 256, 0, stream>>>(kv_tokens, kv_bf, B_ * N_ * E_ / 4);
    gemm_bt_kernel<true><<<dim3(8, 512), 256, 0, stream>>>(kv_bf, Wkv_bf, in_proj_b + E_,
                                                           kvbuf, B_ * N_, 1024, E_);

    for (int t = 0; t < T_; t++) {
        attn_kernel<<<B_ * NH_, 256, 0, stream>>>(kvbuf, s_a_bf, Wc_bf, b_comb, o_bf);
        oproj_oln_kernel<<<64, 256, 0, stream>>>(o_bf, WoutT_bf, out_proj_b, o_ln_g, o_ln_b,
                                                 zbuf, z_ln_g, z_ln_b, u_bf, fused_bf, zn32);
        gemmNK_kernel<2><<<128, 256, 0, stream>>>(u_bf, Wgc_bf, gate_b, cand_b, zn32, fused_bf, 2048, 1536);
        gemmNK_kernel<3><<<128, 256, 0, stream>>>(fused_bf, Ws1_bf, syn1_b, nullptr, nullptr, tbuf_bf, 2048, 1536);
        gemmNK_kernel<4><<<64, 256, 0, stream>>>(tbuf_bf, Ws2_bf, syn2_b, nullptr, nullptr,
                                                 AbufT + (size_t)t * D_ * 64, 1024, 2048);
        switch (t) {
            case 0:  nlm_kernel<1><<<256, 256, 0, stream>>>(AbufT, nlm1w_bf, nlm1_b, nlm2_w, nlm2_b, zbuf, out_zt); break;
            case 1:  nlm_kernel<2><<<256, 256, 0, stream>>>(AbufT, nlm1w_bf, nlm1_b, nlm2_w, nlm2_b, zbuf, out_zt); break;
            case 2:  nlm_kernel<3><<<256, 256, 0, stream>>>(AbufT, nlm1w_bf, nlm1_b, nlm2_w, nlm2_b, zbuf, out_zt); break;
            case 3:  nlm_kernel<4><<<256, 256, 0, stream>>>(AbufT, nlm1w_bf, nlm1_b, nlm2_w, nlm2_b, zbuf, out_zt); break;
            case 4:  nlm_kernel<5><<<256, 256, 0, stream>>>(AbufT, nlm1w_bf, nlm1_b, nlm2_w, nlm2_b, zbuf, out_zt); break;
            case 5:  nlm_kernel<6><<<256, 256, 0, stream>>>(AbufT, nlm1w_bf, nlm1_b, nlm2_w, nlm2_b, zbuf, out_zt); break;
            case 6:  nlm_kernel<7><<<256, 256, 0, stream>>>(AbufT, nlm1w_bf, nlm1_b, nlm2_w, nlm2_b, zbuf, out_zt); break;
            case 7:  nlm_kernel<8><<<256, 256, 0, stream>>>(AbufT, nlm1w_bf, nlm1_b, nlm2_w, nlm2_b, zbuf, out_zt); break;
            case 8:  nlm_kernel<9><<<256, 256, 0, stream>>>(AbufT, nlm1w_bf, nlm1_b, nlm2_w, nlm2_b, zbuf, out_zt); break;
            case 9:  nlm_kernel<10><<<256, 256, 0, stream>>>(AbufT, nlm1w_bf, nlm1_b, nlm2_w, nlm2_b, zbuf, out_zt); break;
            case 10: nlm_kernel<11><<<256, 256, 0, stream>>>(AbufT, nlm1w_bf, nlm1_b, nlm2_w, nlm2_b, zbuf, out_zt); break;
            default: nlm_kernel<12><<<256, 256, 0, stream>>>(AbufT, nlm1w_bf, nlm1_b, nlm2_w, nlm2_b, zbuf, out_zt); break;
        }
        synchead_kernel<<<64, 256, 0, stream>>>(zbuf, act_l, act_r, out_l, out_r, raw_r_act, raw_r_out,
                                                head_w, head_b, a_a, b_a, s_a_bf, a_o, b_o,
                                                out_logits, out_cert, t);
    }
}

// Round 7
// 1339.895 us; speedup vs baseline: 11.0451x; 1.3050x over previous
//
#include <hip/hip_runtime.h>
#include <hip/hip_bf16.h>

#define B_ 64
#define N_ 1024
#define E_ 512
#define D_ 1024
#define M_ 16
#define T_ 12
#define P_ 2048
#define HS_ 2048
#define HN_ 64
#define C_ 4
#define NH_ 8
#define DH_ 64

typedef __attribute__((ext_vector_type(8))) short bf16x8;
typedef __attribute__((ext_vector_type(4))) float f32x4;

__device__ __forceinline__ float bf2f(unsigned int u) {
    union { unsigned int i; float f; } c; c.i = (u & 0xffffu) << 16; return c.f;
}
__device__ __forceinline__ unsigned short f2bf(float f) {
    union { float f; unsigned int i; } c; c.f = f;
    unsigned int x = c.i;
    unsigned int r = x + 0x7fffu + ((x >> 16) & 1u);
    return (unsigned short)(r >> 16);
}

// ---------------- init state ----------------
__global__ void init_kernel(unsigned short* s_a_bf, float* a_a, float* b_a, float* a_o, float* b_o, float* z) {
    int i = blockIdx.x * 256 + threadIdx.x;
    if (i < B_ * P_) { a_a[i] = 0.f; b_a[i] = 1.f; a_o[i] = 0.f; b_o[i] = 1.f; s_a_bf[i] = 0; }
    if (i < B_ * D_) z[i] = 0.f;
}

// ---------------- f32 -> bf16 conversion ----------------
__global__ __launch_bounds__(256) void cvt_bf16_kernel(const float* __restrict__ in,
                                                       unsigned short* __restrict__ out, int n4) {
    int i = blockIdx.x * 256 + threadIdx.x;
    if (i < n4) {
        float4 v = ((const float4*)in)[i];
        ushort4 o;
        o.x = f2bf(v.x); o.y = f2bf(v.y); o.z = f2bf(v.z); o.w = f2bf(v.w);
        ((ushort4*)out)[i] = o;
    }
}

// ---------------- interleave gate/cand rows ----------------
__global__ __launch_bounds__(256) void cvt_ilv_kernel(const float* __restrict__ g,
                                                      const float* __restrict__ c,
                                                      unsigned short* __restrict__ out) {
    int r = blockIdx.x;  // 0..2047
    const float* src = (r & 1) ? (c + (size_t)(r >> 1) * 1536) : (g + (size_t)(r >> 1) * 1536);
    for (int k = threadIdx.x * 4; k < 1536; k += 1024) {
        float4 v = *(const float4*)(src + k);
        ushort4 o;
        o.x = f2bf(v.x); o.y = f2bf(v.y); o.z = f2bf(v.z); o.w = f2bf(v.w);
        *(ushort4*)(out + (size_t)r * 1536 + k) = o;
    }
}

// ---------------- transpose + cvt: out[c][r] = bf16(in[r][c]) ----------------
__global__ __launch_bounds__(256) void transpose_cvt_kernel(const float* __restrict__ in,
                                                            unsigned short* __restrict__ out,
                                                            int R, int Ccols) {
    __shared__ float tb[32][33];
    int c0 = blockIdx.x * 32, r0 = blockIdx.y * 32;
    int tx = threadIdx.x & 31, ty = threadIdx.x >> 5;
#pragma unroll
    for (int i = 0; i < 32; i += 8) tb[ty + i][tx] = in[(size_t)(r0 + ty + i) * Ccols + c0 + tx];
    __syncthreads();
#pragma unroll
    for (int i = 0; i < 32; i += 8) out[(size_t)(c0 + ty + i) * R + r0 + tx] = f2bf(tb[tx][ty + i]);
}

// ---------------- combined query bias: bc = Wq@q_b + bq ----------------
__global__ __launch_bounds__(256) void bcomb_kernel(const float* __restrict__ in_proj_w,
                                                    const float* __restrict__ in_proj_b,
                                                    const float* __restrict__ q_b,
                                                    float* __restrict__ bc) {
    int e = blockIdx.x * 256 + threadIdx.x;
    if (e < E_) {
        const float* wr = in_proj_w + (size_t)e * E_;
        float s = in_proj_b[e];
        for (int k = 0; k < E_; k += 4) {
            float4 w4 = *(const float4*)(wr + k);
            float4 q4 = *(const float4*)(q_b + k);
            s += w4.x * q4.x + w4.y * q4.y + w4.z * q4.z + w4.w * q4.w;
        }
        bc[e] = s;
    }
}

// ---------------- br[h*512+j] = sum_e Wk[h*64+e][j] * bc[h*64+e] ----------------
__global__ __launch_bounds__(256) void br_kernel(const float* __restrict__ in_proj_w,
                                                 const float* __restrict__ bc,
                                                 float* __restrict__ br) {
    int g = blockIdx.x * 256 + threadIdx.x;  // 0..4095
    int h = g >> 9, j = g & 511;
    const float* Wk = in_proj_w + (size_t)E_ * E_;
    float s = 0.f;
    for (int e = 0; e < 64; e++) {
        s += Wk[(size_t)(h * 64 + e) * E_ + j] * bc[h * 64 + e];
    }
    br[g] = s;
}

// ---------------- big bf16 MFMA GEMM (128x128 tile) + XCD swizzle ----------------
template <bool HAS_BIAS>
__global__ __launch_bounds__(256) void gemm_bt_kernel(const unsigned short* __restrict__ A,
                                                      const unsigned short* __restrict__ Bt,
                                                      const float* __restrict__ bias,
                                                      unsigned short* __restrict__ C,
                                                      int M, int N, int K) {
    __shared__ __align__(16) unsigned short ldsA[2][4096];
    __shared__ __align__(16) unsigned short ldsB[2][4096];
    int id = blockIdx.y * gridDim.x + blockIdx.x;
    int nwg = gridDim.x * gridDim.y;
    int swz = (id & 7) * (nwg >> 3) + (id >> 3);
    int bx = swz % gridDim.x, by = swz / gridDim.x;
    int m0 = by * 128;
    int n0 = bx * 128;
    int tid = threadIdx.x;
    int wv = tid >> 6, l = tid & 63;
    int wr = wv >> 1, wc = wv & 1;
    int lr = l & 15, lg = l >> 4;
    f32x4 acc[4][4] = {};

    auto stage = [&](int buf, int kt) {
        int k0 = kt * 32;
#pragma unroll
        for (int i = 0; i < 2; i++) {
            int tsk = tid + 256 * i;
            int r = tsk >> 2, g = tsk & 3;
            int gs = (g ^ (r & 3)) * 8;
            __builtin_amdgcn_global_load_lds(
                (const __attribute__((address_space(1))) void*)(A + (size_t)(m0 + r) * K + k0 + gs),
                (__attribute__((address_space(3))) void*)&ldsA[buf][tsk * 8], 16, 0, 0);
        }
#pragma unroll
        for (int i = 0; i < 2; i++) {
            int tsk = tid + 256 * i;
            int r = tsk >> 2, g = tsk & 3;
            int gs = (g ^ (r & 3)) * 8;
            __builtin_amdgcn_global_load_lds(
                (const __attribute__((address_space(1))) void*)(Bt + (size_t)(n0 + r) * K + k0 + gs),
                (__attribute__((address_space(3))) void*)&ldsB[buf][tsk * 8], 16, 0, 0);
        }
    };

    int nt = K >> 5;
    stage(0, 0);
    for (int t = 0; t < nt; t++) {
        int cur = t & 1;
        if (t + 1 < nt) {
            stage(cur ^ 1, t + 1);
            asm volatile("s_waitcnt vmcnt(4)" ::: "memory");
        } else {
            asm volatile("s_waitcnt vmcnt(0)" ::: "memory");
        }
        __builtin_amdgcn_s_barrier();
        bf16x8 af[4], bfr[4];
#pragma unroll
        for (int mi = 0; mi < 4; mi++) {
            int r = wr * 64 + mi * 16 + lr;
            af[mi] = *(const bf16x8*)&ldsA[cur][r * 32 + ((lg ^ (r & 3)) << 3)];
        }
#pragma unroll
        for (int ni = 0; ni < 4; ni++) {
            int c = wc * 64 + ni * 16 + lr;
            bfr[ni] = *(const bf16x8*)&ldsB[cur][c * 32 + ((lg ^ (c & 3)) << 3)];
        }
#pragma unroll
        for (int mi = 0; mi < 4; mi++)
#pragma unroll
            for (int ni = 0; ni < 4; ni++)
                acc[mi][ni] = __builtin_amdgcn_mfma_f32_16x16x32_bf16(af[mi], bfr[ni], acc[mi][ni], 0, 0, 0);
        __builtin_amdgcn_s_barrier();
    }
#pragma unroll
    for (int ni = 0; ni < 4; ni++) {
        int col = n0 + wc * 64 + ni * 16 + lr;
        float bv = HAS_BIAS ? bias[col] : 0.0f;
#pragma unroll
        for (int mi = 0; mi < 4; mi++) {
            int row = m0 + wr * 64 + mi * 16 + lg * 4;
#pragma unroll
            for (int r = 0; r < 4; r++) {
                C[(size_t)(row + r) * N + col] = f2bf(acc[mi][ni][r] + bv);
            }
        }
    }
}

// ---------------- batched (z=head) strided GEMM for G: C_z = A_z @ Bt_z^T ----------------
__global__ __launch_bounds__(256) void gemm_hb_kernel(const unsigned short* __restrict__ A0, int lda, size_t sAz,
                                                      const unsigned short* __restrict__ B0, int ldb, size_t sBz,
                                                      unsigned short* __restrict__ C0, int ldc, size_t sCz,
                                                      int K) {
    __shared__ __align__(16) unsigned short ldsA[2][4096];
    __shared__ __align__(16) unsigned short ldsB[2][4096];
    const unsigned short* A = A0 + blockIdx.z * sAz;
    const unsigned short* Bt = B0 + blockIdx.z * sBz;
    unsigned short* C = C0 + blockIdx.z * sCz;
    int m0 = blockIdx.y * 128, n0 = blockIdx.x * 128;
    int tid = threadIdx.x;
    int wv = tid >> 6, l = tid & 63;
    int wr = wv >> 1, wc = wv & 1;
    int lr = l & 15, lg = l >> 4;
    f32x4 acc[4][4] = {};

    auto stage = [&](int buf, int kt) {
        int k0 = kt * 32;
#pragma unroll
        for (int i = 0; i < 2; i++) {
            int tsk = tid + 256 * i;
            int r = tsk >> 2, g = tsk & 3;
            int gs = (g ^ (r & 3)) * 8;
            __builtin_amdgcn_global_load_lds(
                (const __attribute__((address_space(1))) void*)(A + (size_t)(m0 + r) * lda + k0 + gs),
                (__attribute__((address_space(3))) void*)&ldsA[buf][tsk * 8], 16, 0, 0);
        }
#pragma unroll
        for (int i = 0; i < 2; i++) {
            int tsk = tid + 256 * i;
            int r = tsk >> 2, g = tsk & 3;
            int gs = (g ^ (r & 3)) * 8;
            __builtin_amdgcn_global_load_lds(
                (const __attribute__((address_space(1))) void*)(Bt + (size_t)(n0 + r) * ldb + k0 + gs),
                (__attribute__((address_space(3))) void*)&ldsB[buf][tsk * 8], 16, 0, 0);
        }
    };

    int nt = K >> 5;
    stage(0, 0);
    for (int t = 0; t < nt; t++) {
        int cur = t & 1;
        if (t + 1 < nt) {
            stage(cur ^ 1, t + 1);
            asm volatile("s_waitcnt vmcnt(4)" ::: "memory");
        } else {
            asm volatile("s_waitcnt vmcnt(0)" ::: "memory");
        }
        __builtin_amdgcn_s_barrier();
        bf16x8 af[4], bfr[4];
#pragma unroll
        for (int mi = 0; mi < 4; mi++) {
            int r = wr * 64 + mi * 16 + lr;
            af[mi] = *(const bf16x8*)&ldsA[cur][r * 32 + ((lg ^ (r & 3)) << 3)];
        }
#pragma unroll
        for (int ni = 0; ni < 4; ni++) {
            int c = wc * 64 + ni * 16 + lr;
            bfr[ni] = *(const bf16x8*)&ldsB[cur][c * 32 + ((lg ^ (c & 3)) << 3)];
        }
#pragma unroll
        for (int mi = 0; mi < 4; mi++)
#pragma unroll
            for (int ni = 0; ni < 4; ni++)
                acc[mi][ni] = __builtin_amdgcn_mfma_f32_16x16x32_bf16(af[mi], bfr[ni], acc[mi][ni], 0, 0, 0);
        __builtin_amdgcn_s_barrier();
    }
#pragma unroll
    for (int ni = 0; ni < 4; ni++) {
        int col = n0 + wc * 64 + ni * 16 + lr;
#pragma unroll
        for (int mi = 0; mi < 4; mi++) {
            int row = m0 + wr * 64 + mi * 16 + lg * 4;
#pragma unroll
            for (int r = 0; r < 4; r++) {
                C[(size_t)(row + r) * ldc + col] = f2bf(acc[mi][ni][r]);
            }
        }
    }
}

// ---------------- fused batch-64 GEMM: 64x16 tile, 4-wave K-split, in-block reduce + epilogue ----------------
// EPI 0: bf16 out, 0.125*(s+bias) (r). 1: f32 plain (opre). 2: gate/cand z_bar. 3: gelu bf16. 4: f32+bias transposed.
template <int EPI>
__global__ __launch_bounds__(256) void gemmNK_kernel(const unsigned short* __restrict__ A,
                                                     const unsigned short* __restrict__ W,
                                                     const float* __restrict__ bias0,
                                                     const float* __restrict__ bias1,
                                                     const float* __restrict__ zn32,
                                                     void* __restrict__ outp,
                                                     int N, int K) {
    __shared__ __align__(16) unsigned short ldsA[4][2][2048];
    __shared__ __align__(16) unsigned short ldsB[4][2][512];
    int n0 = blockIdx.x * 16;
    int tid = threadIdx.x;
    int w = tid >> 6, l = tid & 63;
    int Kw = K >> 2;
    int kb = w * Kw;
    int lr = l & 15, lg = l >> 4;
    int ar = l >> 2, ag = l & 3;
    f32x4 acc[4] = {};

    auto stage = [&](int buf, int kt) {
        int k0 = kb + (kt << 5);
#pragma unroll
        for (int i = 0; i < 4; i++) {
            int row = i * 16 + ar;
            int gs = (ag ^ (row & 3)) << 3;
            __builtin_amdgcn_global_load_lds(
                (const __attribute__((address_space(1))) void*)(A + (size_t)row * K + k0 + gs),
                (__attribute__((address_space(3))) void*)&ldsA[w][buf][i * 512 + l * 8], 16, 0, 0);
        }
        {
            int col = ar;
            int gs = (ag ^ (col & 3)) << 3;
            __builtin_amdgcn_global_load_lds(
                (const __attribute__((address_space(1))) void*)(W + (size_t)(n0 + col) * K + k0 + gs),
                (__attribute__((address_space(3))) void*)&ldsB[w][buf][l * 8], 16, 0, 0);
        }
    };

    int nt = Kw >> 5;
    stage(0, 0);
    for (int t = 0; t < nt; t++) {
        int cur = t & 1;
        if (t + 1 < nt) {
            stage(cur ^ 1, t + 1);
            asm volatile("s_waitcnt vmcnt(5)" ::: "memory");
        } else {
            asm volatile("s_waitcnt vmcnt(0)" ::: "memory");
        }
        bf16x8 bf = *(const bf16x8*)&ldsB[w][cur][lr * 32 + ((lg ^ (lr & 3)) << 3)];
#pragma unroll
        for (int mi = 0; mi < 4; mi++) {
            int rr = mi * 16 + lr;
            bf16x8 af = *(const bf16x8*)&ldsA[w][cur][rr * 32 + ((lg ^ (rr & 3)) << 3)];
            acc[mi] = __builtin_amdgcn_mfma_f32_16x16x32_bf16(af, bf, acc[mi], 0, 0, 0);
        }
    }
    __syncthreads();
    float* red = (float*)&ldsA[0][0][0];  // [4][64][16]
#pragma unroll
    for (int mi = 0; mi < 4; mi++) {
        int row = mi * 16 + lg * 4;
#pragma unroll
        for (int q = 0; q < 4; q++) red[w * 1024 + (row + q) * 16 + lr] = acc[mi][q];
    }
    __syncthreads();
    int b = tid >> 2, c4 = (tid & 3) << 2;
    f32x4 s = *(f32x4*)&red[b * 16 + c4];
#pragma unroll
    for (int ww = 1; ww < 4; ww++) {
        f32x4 v = *(f32x4*)&red[ww * 1024 + b * 16 + c4];
        s[0] += v[0]; s[1] += v[1]; s[2] += v[2]; s[3] += v[3];
    }
    int col = n0 + c4;
    if (EPI == 0) {
        unsigned short* out = (unsigned short*)outp;
        ushort4 o;
        o.x = f2bf(0.125f * (s[0] + bias0[col + 0]));
        o.y = f2bf(0.125f * (s[1] + bias0[col + 1]));
        o.z = f2bf(0.125f * (s[2] + bias0[col + 2]));
        o.w = f2bf(0.125f * (s[3] + bias0[col + 3]));
        *(ushort4*)(out + (size_t)b * N + col) = o;
    } else if (EPI == 1) {
        float* out = (float*)outp;
        *(f32x4*)(out + (size_t)b * N + col) = s;
    } else if (EPI == 2) {
        unsigned short* out = (unsigned short*)outp;
        int j0 = col >> 1;
#pragma unroll
        for (int pp = 0; pp < 2; pp++) {
            int j = j0 + pp;
            float g = 1.0f / (1.0f + expf(-(s[pp * 2] + bias0[j])));
            float h = tanhf(s[pp * 2 + 1] + bias1[j]);
            float zb = (1.0f - g) * zn32[(size_t)b * D_ + j] + g * h;
            out[(size_t)b * 1536 + j] = f2bf(zb);
        }
    } else if (EPI == 3) {
        unsigned short* out = (unsigned short*)outp;
        ushort4 o;
#pragma unroll
        for (int j = 0; j < 4; j++) {
            float pre = s[j] + bias0[col + j];
            float val = 0.5f * pre * (1.0f + erff(pre * 0.70710678118654752f));
            ((unsigned short*)&o)[j] = f2bf(val);
        }
        *(ushort4*)(out + (size_t)b * N + col) = o;
    } else {  // EPI == 4: transposed f32 out[col][b]
        float* out = (float*)outp;
#pragma unroll
        for (int j = 0; j < 4; j++) {
            out[(size_t)(col + j) * 64 + b] = s[j] + bias0[col + j];
        }
    }
}

// ---------------- scores: S[b][h][n] = X[b,n,:] . r[b][h*512+:] (MFMA, X direct from global) ----------------
__global__ __launch_bounds__(256) void scoreX_kernel(const unsigned short* __restrict__ X,
                                                     const unsigned short* __restrict__ r_bf,
                                                     float* __restrict__ S) {
    int b = blockIdx.y;
    int n0 = blockIdx.x * 128;
    int tid = threadIdx.x;
    int wv = tid >> 6, l = tid & 63;
    int lr = l & 15, lg = l >> 4;
    const unsigned short* Xb = X + ((size_t)b * 1024 + n0) * 512;
    const unsigned short* rb = r_bf + (size_t)b * 4096 + (size_t)(lr & 7) * 512 + lg * 8;
    f32x4 acc[2] = {};
#pragma unroll
    for (int kt = 0; kt < 16; kt++) {
        int k0 = kt * 32;
        bf16x8 bfrag = *(const bf16x8*)(rb + k0);
#pragma unroll
        for (int mi = 0; mi < 2; mi++) {
            int row = (wv * 2 + mi) * 16 + lr;
            bf16x8 afrag = *(const bf16x8*)(Xb + (size_t)row * 512 + k0 + lg * 8);
            acc[mi] = __builtin_amdgcn_mfma_f32_16x16x32_bf16(afrag, bfrag, acc[mi], 0, 0, 0);
        }
    }
    if (lr < 8) {
#pragma unroll
        for (int mi = 0; mi < 2; mi++) {
            int rowbase = (wv * 2 + mi) * 16 + lg * 4;
#pragma unroll
            for (int q = 0; q < 4; q++) {
                S[((size_t)b * 8 + lr) * 1024 + n0 + rowbase + q] = acc[mi][q];
            }
        }
    }
}

// ---------------- softmax(S) + V-pass per (b,h) ----------------
__global__ __launch_bounds__(256) void attnV_kernel(const float* __restrict__ S,
                                                    const unsigned short* __restrict__ vbuf,
                                                    unsigned short* __restrict__ o_bf) {
    int bh = blockIdx.x;
    int b = bh >> 3, h = bh & 7;
    __shared__ float sc[N_];
    __shared__ float red[8];
    __shared__ float opart[4][DH_];
    int tid = threadIdx.x;
    int w = tid >> 6, lane = tid & 63;
    const float* Ss = S + ((size_t)b * 8 + h) * 1024;
    float myv[4];
#pragma unroll
    for (int i = 0; i < 4; i++) myv[i] = Ss[tid + i * 256];
    float m = fmaxf(fmaxf(myv[0], myv[1]), fmaxf(myv[2], myv[3]));
#pragma unroll
    for (int off = 32; off >= 1; off >>= 1) m = fmaxf(m, __shfl_xor(m, off, 64));
    if (lane == 0) red[w] = m;
    __syncthreads();
    m = fmaxf(fmaxf(red[0], red[1]), fmaxf(red[2], red[3]));
    float s = 0.f;
#pragma unroll
    for (int i = 0; i < 4; i++) {
        float e = expf(myv[i] - m);
        sc[tid + i * 256] = e;
        s += e;
    }
#pragma unroll
    for (int off = 32; off >= 1; off >>= 1) s += __shfl_xor(s, off, 64);
    if (lane == 0) red[4 + w] = s;
    __syncthreads();
    float inv = 1.0f / (red[4] + red[5] + red[6] + red[7]);
    const unsigned short* vb = vbuf + (size_t)b * 1024 * 512 + h * DH_;
    int ng = lane >> 4, d4 = (lane & 15) << 2;
    float a0 = 0.f, a1 = 0.f, a2 = 0.f, a3 = 0.f;
    int n0 = w * 256;
    for (int i = 0; i < 64; i++) {
        int n = n0 + i * 4 + ng;
        uint2 pv = *(const uint2*)(vb + (size_t)n * 512 + d4);
        float sv = sc[n];
        a0 += sv * bf2f(pv.x);
        a1 += sv * bf2f(pv.x >> 16);
        a2 += sv * bf2f(pv.y);
        a3 += sv * bf2f(pv.y >> 16);
    }
    a0 += __shfl_xor(a0, 16, 64); a0 += __shfl_xor(a0, 32, 64);
    a1 += __shfl_xor(a1, 16, 64); a1 += __shfl_xor(a1, 32, 64);
    a2 += __shfl_xor(a2, 16, 64); a2 += __shfl_xor(a2, 32, 64);
    a3 += __shfl_xor(a3, 16, 64); a3 += __shfl_xor(a3, 32, 64);
    if (lane < 16) {
        opart[w][d4 + 0] = a0;
        opart[w][d4 + 1] = a1;
        opart[w][d4 + 2] = a2;
        opart[w][d4 + 3] = a3;
    }
    __syncthreads();
    if (tid < DH_) {
        float r = (opart[0][tid] + opart[1][tid] + opart[2][tid] + opart[3][tid]) * inv;
        o_bf[(size_t)b * E_ + h * DH_ + tid] = f2bf(r);
    }
}

// ---------------- reduce oproj pre (f32) + LN(o) + LN(z) ----------------
__global__ __launch_bounds__(256) void reduce_oln_kernel(const float* __restrict__ opre,
                                                         const float* __restrict__ bout,
                                                         const float* __restrict__ og,
                                                         const float* __restrict__ obv,
                                                         const float* __restrict__ z,
                                                         const float* __restrict__ zg,
                                                         const float* __restrict__ zbv,
                                                         unsigned short* __restrict__ u_bf,
                                                         unsigned short* __restrict__ fused_bf,
                                                         float* __restrict__ zn32) {
    int b = blockIdx.x, tid = threadIdx.x;
    __shared__ float red[16];
    float v[2];
#pragma unroll
    for (int i = 0; i < 2; i++) {
        int e = tid + i * 256;
        v[i] = opre[(size_t)b * E_ + e] + bout[e];
    }
    int w = tid >> 6, lane = tid & 63;
    float s1 = v[0] + v[1];
    float s2 = v[0] * v[0] + v[1] * v[1];
#pragma unroll
    for (int off = 32; off >= 1; off >>= 1) { s1 += __shfl_xor(s1, off, 64); s2 += __shfl_xor(s2, off, 64); }
    if (lane == 0) { red[w] = s1; red[4 + w] = s2; }
    __syncthreads();
    s1 = red[0] + red[1] + red[2] + red[3];
    s2 = red[4] + red[5] + red[6] + red[7];
    float mean = s1 * (1.0f / 512.0f);
    float var = s2 * (1.0f / 512.0f) - mean * mean;
    float rstd = 1.0f / sqrtf(var + 1e-5f);
#pragma unroll
    for (int i = 0; i < 2; i++) {
        int e = tid + i * 256;
        unsigned short val = f2bf((v[i] - mean) * rstd * og[e] + obv[e]);
        u_bf[(size_t)b * 1536 + D_ + e] = val;
        fused_bf[(size_t)b * 1536 + D_ + e] = val;
    }
    float zl[4];
    float t1 = 0.f, t2 = 0.f;
#pragma unroll
    for (int i = 0; i < 4; i++) {
        int d = tid + i * 256;
        zl[i] = z[(size_t)b * D_ + d];
        t1 += zl[i]; t2 += zl[i] * zl[i];
    }
#pragma unroll
    for (int off = 32; off >= 1; off >>= 1) { t1 += __shfl_xor(t1, off, 64); t2 += __shfl_xor(t2, off, 64); }
    __syncthreads();
    if (lane == 0) { red[8 + w] = t1; red[12 + w] = t2; }
    __syncthreads();
    t1 = red[8] + red[9] + red[10] + red[11];
    t2 = red[12] + red[13] + red[14] + red[15];
    float zmean = t1 * (1.0f / 1024.0f);
    float zvar = t2 * (1.0f / 1024.0f) - zmean * zmean;
    float zr = 1.0f / sqrtf(zvar + 1e-5f);
#pragma unroll
    for (int i = 0; i < 4; i++) {
        int d = tid + i * 256;
        float zn = (zl[i] - zmean) * zr * zg[d] + zbv[d];
        u_bf[(size_t)b * 1536 + d] = f2bf(zn);
        zn32[(size_t)b * D_ + d] = zn;
    }
}

// ---------------- NLM over transposed history Abuf_T [t][d][b], bf16 w1 ----------------
template <int NT>
__global__ __launch_bounds__(256) void nlm_kernel(const float* __restrict__ AbufT,
                                                  const unsigned short* __restrict__ w1g_bf,
                                                  const float* __restrict__ b1g,
                                                  const float* __restrict__ w2g,
                                                  const float* __restrict__ b2g,
                                                  float* __restrict__ z,
                                                  float* __restrict__ zt) {
    __shared__ float w1s[4][2048];
    __shared__ float b1s[4][128];
    __shared__ float w2s[4][128];
    __shared__ float b2s[4][2];
    int tid = threadIdx.x;
    int w = tid >> 6, lane = tid & 63;
    int d = blockIdx.x * 4 + w;
    for (int i = lane * 2; i < 2048; i += 128) {
        unsigned int pk = *(const unsigned int*)(w1g_bf + (size_t)d * 2048 + i);
        w1s[w][i] = bf2f(pk);
        w1s[w][i + 1] = bf2f(pk >> 16);
    }
    for (int i = lane; i < 128; i += 64) {
        b1s[w][i] = b1g[(size_t)d * 128 + i];
        w2s[w][i] = w2g[(size_t)d * 128 + i];
    }
    if (lane < 2) b2s[w][lane] = b2g[d * 2 + lane];
    __syncthreads();
    const int b = lane;
    float av[NT];
#pragma unroll
    for (int s = 0; s < NT; s++) av[s] = AbufT[((size_t)s * D_ + d) * 64 + b];
    constexpr int moff = M_ - NT;
    float o0 = b2s[w][0], o1 = b2s[w][1];
    for (int hh = 0; hh < 64; hh++) {
        float a = b1s[w][hh], bb = b1s[w][hh + 64];
#pragma unroll
        for (int s = 0; s < NT; s++) {
            float x = av[s];
            a += x * w1s[w][(s + moff) * 128 + hh];
            bb += x * w1s[w][(s + moff) * 128 + hh + 64];
        }
        float z1 = a / (1.0f + expf(-bb));
        o0 += z1 * w2s[w][hh * 2];
        o1 += z1 * w2s[w][hh * 2 + 1];
    }
    float zv = o0 / (1.0f + expf(-o1));
    z[(size_t)b * D_ + d] = zv;
    zt[((size_t)b * T_ + (NT - 1)) * D_ + d] = zv;
}

// ---------------- pair-sync update + head + certainty ----------------
__global__ __launch_bounds__(256) void synchead_kernel(const float* __restrict__ z,
                                                       const int* __restrict__ act_l, const int* __restrict__ act_r,
                                                       const int* __restrict__ out_l, const int* __restrict__ out_r,
                                                       const float* __restrict__ raw_a, const float* __restrict__ raw_o,
                                                       const float* __restrict__ head_w, const float* __restrict__ head_b,
                                                       float* __restrict__ a_a, float* __restrict__ b_a,
                                                       unsigned short* __restrict__ s_a_bf,
                                                       float* __restrict__ a_o, float* __restrict__ b_o,
                                                       float* __restrict__ out_logits, float* __restrict__ out_cert, int t) {
    int b = blockIdx.x, tid = threadIdx.x;
    __shared__ float zv[D_];
    __shared__ float red[4][4];
    for (int i = tid; i < D_; i += 256) zv[i] = z[(size_t)b * D_ + i];
    __syncthreads();
    float l0 = 0.f, l1 = 0.f, l2 = 0.f, l3 = 0.f;
    for (int p = tid; p < P_; p += 256) {
        size_t ip = (size_t)b * P_ + p;
        float zl = zv[act_l[p]], zr = zv[act_r[p]];
        float da = 1.0f / (1.0f + expf(raw_a[p]));
        float aa = da * a_a[ip] + zl * zr;
        float ba = da * b_a[ip] + 1.0f;
        a_a[ip] = aa; b_a[ip] = ba;
        s_a_bf[(size_t)b * P_ + p] = f2bf(aa / sqrtf(ba + 1e-8f));
        float zlo = zv[out_l[p]], zro = zv[out_r[p]];
        float dz = 1.0f / (1.0f + expf(raw_o[p]));
        float ao = dz * a_o[ip] + zlo * zro;
        float bo = dz * b_o[ip] + 1.0f;
        a_o[ip] = ao; b_o[ip] = bo;
        float so = ao / sqrtf(bo + 1e-8f);
        l0 += so * head_w[p];
        l1 += so * head_w[P_ + p];
        l2 += so * head_w[2 * P_ + p];
        l3 += so * head_w[3 * P_ + p];
    }
    int w = tid >> 6, lane = tid & 63;
#pragma unroll
    for (int off = 32; off >= 1; off >>= 1) {
        l0 += __shfl_xor(l0, off, 64);
        l1 += __shfl_xor(l1, off, 64);
        l2 += __shfl_xor(l2, off, 64);
        l3 += __shfl_xor(l3, off, 64);
    }
    if (lane == 0) { red[w][0] = l0; red[w][1] = l1; red[w][2] = l2; red[w][3] = l3; }
    __syncthreads();
    if (tid == 0) {
        float lg[4];
#pragma unroll
        for (int c = 0; c < 4; c++) {
            lg[c] = red[0][c] + red[1][c] + red[2][c] + red[3][c] + head_b[c];
            out_logits[((size_t)b * C_ + c) * T_ + t] = lg[c];
        }
        float m = fmaxf(fmaxf(lg[0], lg[1]), fmaxf(lg[2], lg[3]));
        float e0 = expf(lg[0] - m), e1 = expf(lg[1] - m), e2 = expf(lg[2] - m), e3 = expf(lg[3] - m);
        float inv = 1.0f / (e0 + e1 + e2 + e3);
        float ent = 0.f, pp;
        pp = fmaxf(e0 * inv, 1e-8f); ent -= pp * logf(pp);
        pp = fmaxf(e1 * inv, 1e-8f); ent -= pp * logf(pp);
        pp = fmaxf(e2 * inv, 1e-8f); ent -= pp * logf(pp);
        pp = fmaxf(e3 * inv, 1e-8f); ent -= pp * logf(pp);
        out_cert[(size_t)b * T_ + t] = 1.0f - ent * (1.0f / 1.3862943611198906f);
    }
}

extern "C" void kernel_launch(void* const* d_in, const int* in_sizes, int n_in,
                              void* d_out, int out_size, void* d_ws, size_t ws_size,
                              hipStream_t stream) {
    const float* kv_tokens  = (const float*)d_in[0];
    const float* raw_r_act  = (const float*)d_in[1];
    const float* raw_r_out  = (const float*)d_in[2];
    const float* q_w        = (const float*)d_in[3];
    const float* q_b        = (const float*)d_in[4];
    const float* in_proj_w  = (const float*)d_in[5];
    const float* in_proj_b  = (const float*)d_in[6];
    const float* out_proj_w = (const float*)d_in[7];
    const float* out_proj_b = (const float*)d_in[8];
    const float* z_ln_g     = (const float*)d_in[9];
    const float* z_ln_b     = (const float*)d_in[10];
    const float* o_ln_g     = (const float*)d_in[11];
    const float* o_ln_b     = (const float*)d_in[12];
    const float* gate_w     = (const float*)d_in[13];
    const float* gate_b     = (const float*)d_in[14];
    const float* cand_w     = (const float*)d_in[15];
    const float* cand_b     = (const float*)d_in[16];
    const float* syn1_w     = (const float*)d_in[17];
    const float* syn1_b     = (const float*)d_in[18];
    const float* syn2_w     = (const float*)d_in[19];
    const float* syn2_b     = (const float*)d_in[20];
    const float* nlm1_w     = (const float*)d_in[21];
    const float* nlm1_b     = (const float*)d_in[22];
    const float* nlm2_w     = (const float*)d_in[23];
    const float* nlm2_b     = (const float*)d_in[24];
    const float* head_w     = (const float*)d_in[25];
    const float* head_b     = (const float*)d_in[26];
    const int* act_l        = (const int*)d_in[27];
    const int* act_r        = (const int*)d_in[28];
    const int* out_l        = (const int*)d_in[29];
    const int* out_r        = (const int*)d_in[30];

    float* out = (float*)d_out;
    float* out_logits = out;                       // [B,C,T]
    float* out_cert = out + B_ * C_ * T_;          // [B,T]
    float* out_zt = out_cert + B_ * T_;            // [B,T,D]

    char* ws = (char*)d_ws;
    size_t off = 0;
    auto alloc = [&](size_t bytes) { void* p = ws + off; off += (bytes + 255) & ~(size_t)255; return p; };
    unsigned short* kv_bf   = (unsigned short*)alloc((size_t)B_ * N_ * E_ * 2);     // 64MB (X)
    unsigned short* vbuf    = (unsigned short*)alloc((size_t)B_ * N_ * E_ * 2);     // 64MB
    unsigned short* Wv_bf   = (unsigned short*)alloc((size_t)E_ * E_ * 2);
    unsigned short* Wq_bf   = (unsigned short*)alloc((size_t)E_ * E_ * 2);
    unsigned short* WkT_bf  = (unsigned short*)alloc((size_t)E_ * E_ * 2);
    unsigned short* qwT_bf  = (unsigned short*)alloc((size_t)P_ * E_ * 2);
    unsigned short* WcT_bf  = (unsigned short*)alloc((size_t)P_ * E_ * 2);
    unsigned short* Gmat    = (unsigned short*)alloc((size_t)4096 * P_ * 2);        // 16MB
    unsigned short* Wgc_bf  = (unsigned short*)alloc((size_t)2048 * 1536 * 2);
    unsigned short* Ws1_bf  = (unsigned short*)alloc((size_t)2048 * 1536 * 2);
    unsigned short* Ws2_bf  = (unsigned short*)alloc((size_t)1024 * 2048 * 2);
    unsigned short* Wout_bf = (unsigned short*)alloc((size_t)E_ * E_ * 2);
    unsigned short* nlm1w_bf= (unsigned short*)alloc((size_t)1024 * 2048 * 2);
    float* bc   = (float*)alloc(E_ * 4);
    float* brv  = (float*)alloc(4096 * 4);
    unsigned short* s_a_bf  = (unsigned short*)alloc((size_t)B_ * P_ * 2);
    unsigned short* r_bf    = (unsigned short*)alloc((size_t)B_ * 4096 * 2);
    float* Sbuf = (float*)alloc((size_t)B_ * 8 * N_ * 4);                           // 2MB
    unsigned short* o_bf    = (unsigned short*)alloc((size_t)B_ * E_ * 2);
    unsigned short* u_bf    = (unsigned short*)alloc((size_t)B_ * 1536 * 2);
    unsigned short* fused_bf= (unsigned short*)alloc((size_t)B_ * 1536 * 2);
    unsigned short* tbuf_bf = (unsigned short*)alloc((size_t)B_ * HS_ * 2);
    float* opre = (float*)alloc((size_t)B_ * E_ * 4);
    float* zn32 = (float*)alloc((size_t)B_ * D_ * 4);
    float* a_a  = (float*)alloc((size_t)B_ * P_ * 4);
    float* b_a  = (float*)alloc((size_t)B_ * P_ * 4);
    float* a_o  = (float*)alloc((size_t)B_ * P_ * 4);
    float* b_o  = (float*)alloc((size_t)B_ * P_ * 4);
    float* zbuf = (float*)alloc((size_t)B_ * D_ * 4);
    float* AbufT = (float*)alloc((size_t)T_ * D_ * B_ * 4);

    init_kernel<<<512, 256, 0, stream>>>(s_a_bf, a_a, b_a, a_o, b_o, zbuf);

    // --- one-time weight prep ---
    cvt_bf16_kernel<<<(B_ * N_ * E_ / 4) / 256, 256, 0, stream>>>(kv_tokens, kv_bf, B_ * N_ * E_ / 4);
    cvt_bf16_kernel<<<256, 256, 0, stream>>>(in_proj_w + (size_t)2 * E_ * E_, Wv_bf, E_ * E_ / 4);
    cvt_bf16_kernel<<<256, 256, 0, stream>>>(in_proj_w, Wq_bf, E_ * E_ / 4);
    transpose_cvt_kernel<<<dim3(16, 16), 256, 0, stream>>>(in_proj_w + (size_t)E_ * E_, WkT_bf, E_, E_);
    transpose_cvt_kernel<<<dim3(P_ / 32, E_ / 32), 256, 0, stream>>>(q_w, qwT_bf, E_, P_);
    bcomb_kernel<<<2, 256, 0, stream>>>(in_proj_w, in_proj_b, q_b, bc);
    br_kernel<<<16, 256, 0, stream>>>(in_proj_w, bc, brv);
    // WcT[p][e] = sum_k q_w[k][p] * Wq[e][k]
    gemm_bt_kernel<false><<<dim3(E_ / 128, P_ / 128), 256, 0, stream>>>(qwT_bf, Wq_bf, nullptr, WcT_bf, P_, E_, E_);
    // G[h*512+j][p] = sum_e WkT[j][h*64+e] * WcT[p][h*64+e]
    gemm_hb_kernel<<<dim3(P_ / 128, E_ / 128, NH_), 256, 0, stream>>>(WkT_bf, E_, 64,
                                                                      WcT_bf, E_, 64,
                                                                      Gmat, P_, (size_t)512 * P_, 64);
    cvt_ilv_kernel<<<2048, 256, 0, stream>>>(gate_w, cand_w, Wgc_bf);
    cvt_bf16_kernel<<<(2048 * 1536 / 4 + 255) / 256, 256, 0, stream>>>(syn1_w, Ws1_bf, 2048 * 1536 / 4);
    cvt_bf16_kernel<<<(1024 * 2048 / 4 + 255) / 256, 256, 0, stream>>>(syn2_w, Ws2_bf, 1024 * 2048 / 4);
    cvt_bf16_kernel<<<(1024 * 2048 / 4 + 255) / 256, 256, 0, stream>>>(nlm1_w, nlm1w_bf, 1024 * 2048 / 4);
    cvt_bf16_kernel<<<256, 256, 0, stream>>>(out_proj_w, Wout_bf, E_ * E_ / 4);
    // V projection only (K never materialized)
    gemm_bt_kernel<true><<<dim3(E_ / 128, B_ * N_ / 128), 256, 0, stream>>>(kv_bf, Wv_bf, in_proj_b + 2 * E_,
                                                                            vbuf, B_ * N_, E_, E_);

    for (int t = 0; t < T_; t++) {
        // r = 0.125 * (s_a @ G^T + br)  [64][4096] bf16
        gemmNK_kernel<0><<<256, 256, 0, stream>>>(s_a_bf, Gmat, brv, nullptr, nullptr, r_bf, 4096, P_);
        // S[b][h][n] = X . r
        scoreX_kernel<<<dim3(8, 64), 256, 0, stream>>>(kv_bf, r_bf, Sbuf);
        // softmax + V
        attnV_kernel<<<B_ * NH_, 256, 0, stream>>>(Sbuf, vbuf, o_bf);
        // opre = o @ Wout^T
        gemmNK_kernel<1><<<32, 256, 0, stream>>>(o_bf, Wout_bf, nullptr, nullptr, nullptr, opre, E_, E_);
        reduce_oln_kernel<<<64, 256, 0, stream>>>(opre, out_proj_b, o_ln_g, o_ln_b,
                                                  zbuf, z_ln_g, z_ln_b, u_bf, fused_bf, zn32);
        gemmNK_kernel<2><<<128, 256, 0, stream>>>(u_bf, Wgc_bf, gate_b, cand_b, zn32, fused_bf, 2048, 1536);
        gemmNK_kernel<3><<<128, 256, 0, stream>>>(fused_bf, Ws1_bf, syn1_b, nullptr, nullptr, tbuf_bf, 2048, 1536);
        gemmNK_kernel<4><<<64, 256, 0, stream>>>(tbuf_bf, Ws2_bf, syn2_b, nullptr, nullptr,
                                                 AbufT + (size_t)t * D_ * 64, 1024, 2048);
        switch (t) {
            case 0:  nlm_kernel<1><<<256, 256, 0, stream>>>(AbufT, nlm1w_bf, nlm1_b, nlm2_w, nlm2_b, zbuf, out_zt); break;
            case 1:  nlm_kernel<2><<<256, 256, 0, stream>>>(AbufT, nlm1w_bf, nlm1_b, nlm2_w, nlm2_b, zbuf, out_zt); break;
            case 2:  nlm_kernel<3><<<256, 256, 0, stream>>>(AbufT, nlm1w_bf, nlm1_b, nlm2_w, nlm2_b, zbuf, out_zt); break;
            case 3:  nlm_kernel<4><<<256, 256, 0, stream>>>(AbufT, nlm1w_bf, nlm1_b, nlm2_w, nlm2_b, zbuf, out_zt); break;
            case 4:  nlm_kernel<5><<<256, 256, 0, stream>>>(AbufT, nlm1w_bf, nlm1_b, nlm2_w, nlm2_b, zbuf, out_zt); break;
            case 5:  nlm_kernel<6><<<256, 256, 0, stream>>>(AbufT, nlm1w_bf, nlm1_b, nlm2_w, nlm2_b, zbuf, out_zt); break;
            case 6:  nlm_kernel<7><<<256, 256, 0, stream>>>(AbufT, nlm1w_bf, nlm1_b, nlm2_w, nlm2_b, zbuf, out_zt); break;
            case 7:  nlm_kernel<8><<<256, 256, 0, stream>>>(AbufT, nlm1w_bf, nlm1_b, nlm2_w, nlm2_b, zbuf, out_zt); break;
            case 8:  nlm_kernel<9><<<256, 256, 0, stream>>>(AbufT, nlm1w_bf, nlm1_b, nlm2_w, nlm2_b, zbuf, out_zt); break;
            case 9:  nlm_kernel<10><<<256, 256, 0, stream>>>(AbufT, nlm1w_bf, nlm1_b, nlm2_w, nlm2_b, zbuf, out_zt); break;
            case 10: nlm_kernel<11><<<256, 256, 0, stream>>>(AbufT, nlm1w_bf, nlm1_b, nlm2_w, nlm2_b, zbuf, out_zt); break;
            default: nlm_kernel<12><<<256, 256, 0, stream>>>(AbufT, nlm1w_bf, nlm1_b, nlm2_w, nlm2_b, zbuf, out_zt); break;
        }
        synchead_kernel<<<64, 256, 0, stream>>>(zbuf, act_l, act_r, out_l, out_r, raw_r_act, raw_r_out,
                                                head_w, head_b, a_a, b_a, s_a_bf, a_o, b_o,
                                                out_logits, out_cert, t);
    }
}